// Round 2
// baseline (933.330 us; speedup 1.0000x reference)
//
#include <hip/hip_runtime.h>
#include <hip/hip_bf16.h>

#define TOKENS 16384
#define MDIM   1024
#define HDIM   4096
#define NEXP   8
#define EGRP   4          // experts per GEMM group (2 groups)
#define CAP    2048
#define NKT1   (MDIM / 64)   // 16 K-tiles for GEMM1
#define NKT2   (HDIM / 64)   // 64 K-tiles for GEMM2

typedef __attribute__((ext_vector_type(8))) short bf16x8;  // 8 bf16 = 4 VGPR
typedef __attribute__((ext_vector_type(4))) float f32x4;

__device__ __forceinline__ short f2bf(float x) {
  unsigned u = __float_as_uint(x);
  unsigned r = (u + 0x7fffu + ((u >> 16) & 1u)) >> 16;
  return (short)r;
}

// round bits to bf16 boundary (RNE), result in high 16 bits
__device__ __forceinline__ unsigned bfbits(float x) {
  unsigned u = __float_as_uint(x);
  return u + 0x7fffu + ((u >> 16) & 1u);
}

__device__ __forceinline__ float gelu_f(float x) {
  // jax.nn.gelu approximate=True
  float u = 1.5957691216057308f * (x + 0.044715f * x * x * x);
  float e = __expf(u);
  return x * (1.f - 1.f / (e + 1.f));
}

// ---------------- gating: logits -> softmax -> argmax; also emit bf16 x ----------------
__global__ __launch_bounds__(256) void gating_kernel(
    const float* __restrict__ x, const float* __restrict__ wg,
    int* __restrict__ idx, float* __restrict__ gate,
    float* __restrict__ mepart, short* __restrict__ xb) {
  __shared__ float me_s[NEXP];
  int tid = threadIdx.x, wid = tid >> 6, lane = tid & 63;
  if (tid < NEXP) me_s[tid] = 0.f;
  __syncthreads();
  int t = blockIdx.x * 4 + wid;
  float acc[NEXP];
#pragma unroll
  for (int e = 0; e < NEXP; e++) acc[e] = 0.f;
  const float4* xr = (const float4*)(x + (size_t)t * MDIM);
  short* xbr = xb + (size_t)t * MDIM + lane * 16;
#pragma unroll
  for (int j = 0; j < 4; j++) {
    float4 xv = xr[lane * 4 + j];
    short4 bv; bv.x = f2bf(xv.x); bv.y = f2bf(xv.y); bv.z = f2bf(xv.z); bv.w = f2bf(xv.w);
    ((short4*)(xbr))[j] = bv;
    int base = lane * 16 + j * 4;
    const float* xp = &xv.x;
#pragma unroll
    for (int i = 0; i < 4; i++) {
      float xi = xp[i];
      const float4* wr = (const float4*)(wg + (size_t)(base + i) * NEXP);
      float4 w0 = wr[0], w1 = wr[1];
      acc[0] += xi * w0.x; acc[1] += xi * w0.y; acc[2] += xi * w0.z; acc[3] += xi * w0.w;
      acc[4] += xi * w1.x; acc[5] += xi * w1.y; acc[6] += xi * w1.z; acc[7] += xi * w1.w;
    }
  }
#pragma unroll
  for (int off = 32; off > 0; off >>= 1)
#pragma unroll
    for (int e = 0; e < NEXP; e++) acc[e] += __shfl_xor(acc[e], off, 64);
  if (lane == 0) {
    float mx = acc[0]; int ai = 0;
#pragma unroll
    for (int e = 1; e < NEXP; e++) if (acc[e] > mx) { mx = acc[e]; ai = e; }
    float ex[NEXP]; float se = 0.f;
#pragma unroll
    for (int e = 0; e < NEXP; e++) { ex[e] = __expf(acc[e] - mx); se += ex[e]; }
    float inv = 1.f / se;
#pragma unroll
    for (int e = 0; e < NEXP; e++) atomicAdd(&me_s[e], ex[e] * inv);
    idx[t] = ai;
    gate[t] = inv;
  }
  __syncthreads();
  if (tid < NEXP) mepart[blockIdx.x * NEXP + tid] = me_s[tid];
}

// ---------------- ordered scan: queue positions + l_aux tail ----------------
__global__ __launch_bounds__(1024) void scan_kernel(
    const int* __restrict__ idx, float* __restrict__ gate,
    int* __restrict__ s2t, int* __restrict__ counts,
    const float* __restrict__ mepart, float* __restrict__ out_tail) {
  __shared__ int wcnt[16][NEXP];
  __shared__ int wbase[16][NEXP];
  __shared__ int totc[NEXP];
  __shared__ float red2[1024];
  int tid = threadIdx.x, wid = tid >> 6, lane = tid & 63;
  unsigned long long ltmask = (1ull << lane) - 1ull;
  int myexp[16], myloc[16];
  int cnt[NEXP];
#pragma unroll
  for (int e = 0; e < NEXP; e++) cnt[e] = 0;
  int base_tok = wid * 1024;
#pragma unroll
  for (int p = 0; p < 16; p++) {
    int e = idx[base_tok + p * 64 + lane];
    myexp[p] = e;
    int pos = 0;
#pragma unroll
    for (int e2 = 0; e2 < NEXP; e2++) {
      unsigned long long b = __ballot(e == e2);
      if (e == e2) pos = cnt[e2] + __popcll(b & ltmask);
      cnt[e2] += __popcll(b);            // wave-uniform
    }
    myloc[p] = pos;
  }
  if (lane < NEXP) wcnt[wid][lane] = cnt[lane];
  __syncthreads();
  if (tid < 128) {
    int w = tid >> 3, e = tid & 7;
    int s = 0;
    for (int w2 = 0; w2 < w; w2++) s += wcnt[w2][e];
    wbase[w][e] = s;
  }
  __syncthreads();
#pragma unroll
  for (int p = 0; p < 16; p++) {
    int i = base_tok + p * 64 + lane;
    int e = myexp[p];
    int loc = wbase[wid][e] + myloc[p];
    if (loc < CAP) s2t[e * CAP + loc] = i;
    else           gate[i] = 0.f;
  }
  if (tid < NEXP) {
    int tot = 0;
#pragma unroll
    for (int w = 0; w < 16; w++) tot += wcnt[w][tid];
    counts[tid] = tot;
    totc[tid] = tot;
  }
  // ---- l_aux + exp_counts tail (absorbed finalize_kernel) ----
  float s = 0.f;
  int e2 = tid & 7;
  for (int r = tid >> 3; r < (TOKENS / 4); r += 128) s += mepart[(size_t)r * NEXP + e2];
  red2[tid] = s;
  __syncthreads();
#pragma unroll
  for (int off = 512; off >= 8; off >>= 1) {
    if (tid < off) red2[tid] += red2[tid + off];
    __syncthreads();
  }
  if (tid == 0) {
    float la = 0.f;
    for (int k = 0; k < NEXP; k++)
      la += (red2[k] / (float)TOKENS) * ((float)totc[k] / (float)TOKENS);
    out_tail[0] = la * (float)NEXP;
  }
  if (tid < NEXP) out_tail[1 + tid] = (float)totc[tid];
}

// ---------------- fp32 [E][R][C] -> bf16 [E][C][R], 64x64 LDS tiles ----------------
__global__ __launch_bounds__(256) void transpose_cvt_kernel(
    const float* __restrict__ in, short* __restrict__ out, int R, int Cc) {
  __shared__ short tile[64][72];   // pad 72: 8B-aligned b64 reads, <=2-way banks
  int e = blockIdx.z;
  const float* in_e = in + (size_t)e * R * Cc;
  short* out_e = out + (size_t)e * R * Cc;
  int r0 = blockIdx.y * 64, c0 = blockIdx.x * 64;
  int tid = threadIdx.x;
#pragma unroll
  for (int i = 0; i < 4; i++) {
    int linear = tid + 256 * i;          // 0..1023
    int r = linear >> 4;                 // 0..63
    int f4 = linear & 15;                // 0..15
    float4 v = *(const float4*)(in_e + (size_t)(r0 + r) * Cc + c0 + f4 * 4);
    int c = f4 * 4;
    tile[c + 0][r] = f2bf(v.x);
    tile[c + 1][r] = f2bf(v.y);
    tile[c + 2][r] = f2bf(v.z);
    tile[c + 3][r] = f2bf(v.w);
  }
  __syncthreads();
#pragma unroll
  for (int i = 0; i < 4; i++) {
    int linear = tid + 256 * i;
    int c = linear >> 4;
    int s4 = linear & 15;
    short4 s;
    s.x = tile[c][s4 * 4 + 0]; s.y = tile[c][s4 * 4 + 1];
    s.z = tile[c][s4 * 4 + 2]; s.w = tile[c][s4 * 4 + 3];
    *(short4*)(out_e + (size_t)(c0 + c) * R + r0 + s4 * 4) = s;
  }
}

// ---------------- phase-boundary helpers (m201 template style) ----------------
__device__ __forceinline__ void bar() {
  asm volatile("" ::: "memory");
  __builtin_amdgcn_s_barrier();
  asm volatile("" ::: "memory");
}
__device__ __forceinline__ void lgkm0() {
  asm volatile("s_waitcnt lgkmcnt(0)" ::: "memory");
  __builtin_amdgcn_sched_barrier(0);
}
__device__ __forceinline__ void vm_bar8() {
  asm volatile("s_waitcnt vmcnt(8)" ::: "memory");
  __builtin_amdgcn_s_barrier();
  asm volatile("" ::: "memory");
}
__device__ __forceinline__ void vm_bar6() {
  asm volatile("s_waitcnt vmcnt(6)" ::: "memory");
  __builtin_amdgcn_s_barrier();
  asm volatile("" ::: "memory");
}
__device__ __forceinline__ void vm_bar0() {
  asm volatile("s_waitcnt vmcnt(0)" ::: "memory");
  __builtin_amdgcn_s_barrier();
  asm volatile("" ::: "memory");
}

#define GLL(gp, lp) __builtin_amdgcn_global_load_lds(                                   \
    (const __attribute__((address_space(1))) void*)(gp),                                \
    (__attribute__((address_space(3))) void*)(lp), 16, 0, 0)

// ---------------- GEMM1: 256x256xBK64, 8 waves, 4-phase (2 barriers/phase) ----------------
// A = gathered xb rows (cap dim), B = W1t [H][M]. MFMA operands swapped:
// D[col=lane&15 -> cap row][row=(lane>>4)*4+j -> H col].
// LDS swizzle: LDS(r, s) = G(r, s ^ (r&7)) at 8-short granularity.
// Per phase (template): GLL prefetch; ds_reads; barrier; lgkmcnt(0)+sched_barrier;
// setprio(1); 16 MFMA k-outer; setprio(0); [vmcnt]; barrier.
// Stage units: A0={rows 0-63,128-191}, A1={64-127,192-255}, B0={h0}, B1={h1}.
// Reads: P1: af0(8)+bf0(4); P2: bf1(4); P3: af1(8); P4: 0.
// Stages (tile t+2 into buf[cur]): P2: A0+B0(4); P3: B1(2); P4: A1(2).
// vmcnt(8) ONCE per tile at end-P4 (outstanding = t+2's 8 -> waits t+1 landed);
// b2 of each phase guarantees reads COMPLETED before next phase's GLL overwrites.
__global__ __launch_bounds__(512, 2) void gemm1_kernel(
    const short* __restrict__ xb, const int* __restrict__ s2t,
    const short* __restrict__ W1t, const float* __restrict__ b1,
    short* __restrict__ Hh, const short* __restrict__ zrow, int eg) {
  __shared__ __align__(16) short ldsA[2][256 * 64];
  __shared__ __align__(16) short ldsB[2][256 * 64];
  int bz = blockIdx.z, bm = blockIdx.y, bn = blockIdx.x;
  int e_abs = eg + bz;
  int tid = threadIdx.x, lane = tid & 63, w = tid >> 6;
  int v = tid >> 3;                  // 0..63: row-within-round selector
  int sl = tid & 7;                  // source 16B slot selector

  // A staging pointers (token gather), rounds q=0..3: row = q*64 + v
  const short* aptr[4];
#pragma unroll
  for (int q = 0; q < 4; q++) {
    int r = q * 64 + v;
    int tok = s2t[e_abs * CAP + bm * 256 + r];
    const short* basep = (tok >= 0) ? (xb + (size_t)tok * MDIM) : zrow;
    aptr[q] = basep + ((sl ^ (r & 7)) * 8);
  }
  // B staging pointers, rounds (h,j): row = j*128 + (v>>5)*64 + (v&31) + h*32
  const short* Be = W1t + ((size_t)e_abs * HDIM + (size_t)bn * 256) * MDIM;
  const short* bptr[2][2];
#pragma unroll
  for (int h = 0; h < 2; h++)
#pragma unroll
    for (int j = 0; j < 2; j++) {
      int r = j * 128 + (v >> 5) * 64 + (v & 31) + h * 32;
      bptr[h][j] = Be + (size_t)r * MDIM + ((sl ^ (r & 7)) * 8);
    }
  asm volatile("" ::: "memory");   // pin gather loads before first stage

  // wave-uniform LDS destination bases (shorts)
  int ldsa_base[4], ldsb_base[2][2];
#pragma unroll
  for (int q = 0; q < 4; q++) ldsa_base[q] = (q * 64 + w * 8) * 64;
#pragma unroll
  for (int h = 0; h < 2; h++)
#pragma unroll
    for (int j = 0; j < 2; j++)
      ldsb_base[h][j] = (j * 128 + h * 32 + (w >> 2) * 64 + (w & 3) * 8) * 64;

  // prologue: tiles 0 and 1 fully staged
  GLL(aptr[0] + 0,        &ldsA[0][ldsa_base[0]]);
  GLL(aptr[2] + 0,        &ldsA[0][ldsa_base[2]]);
  GLL(bptr[0][0] + 0,     &ldsB[0][ldsb_base[0][0]]);
  GLL(bptr[0][1] + 0,     &ldsB[0][ldsb_base[0][1]]);
  GLL(bptr[1][0] + 0,     &ldsB[0][ldsb_base[1][0]]);
  GLL(bptr[1][1] + 0,     &ldsB[0][ldsb_base[1][1]]);
  GLL(aptr[1] + 0,        &ldsA[0][ldsa_base[1]]);
  GLL(aptr[3] + 0,        &ldsA[0][ldsa_base[3]]);
  GLL(aptr[0] + 64,       &ldsA[1][ldsa_base[0]]);
  GLL(aptr[2] + 64,       &ldsA[1][ldsa_base[2]]);
  GLL(bptr[0][0] + 64,    &ldsB[1][ldsb_base[0][0]]);
  GLL(bptr[0][1] + 64,    &ldsB[1][ldsb_base[0][1]]);
  GLL(bptr[1][0] + 64,    &ldsB[1][ldsb_base[1][0]]);
  GLL(bptr[1][1] + 64,    &ldsB[1][ldsb_base[1][1]]);
  GLL(aptr[1] + 64,       &ldsA[1][ldsa_base[1]]);
  GLL(aptr[3] + 64,       &ldsA[1][ldsa_base[3]]);
  vm_bar8();                         // tile 0 landed; tile 1 (8 loads) in flight

  int wm = w >> 2, wn = w & 3;       // 2 x 4 wave grid; per-wave out = 128(cap) x 64(H)
  int ln = lane & 15, q4 = lane >> 4;
  int offk0 = ((q4 ^ (lane & 7)) * 8);
  int offk1 = (((4 + q4) ^ (lane & 7)) * 8);
  int arowbase = wm * 128 + ln;
  int browbase = wn * 64 + ln;

  f32x4 acc[8][4];
  f32x4 zero = {0.f, 0.f, 0.f, 0.f};
#pragma unroll
  for (int a = 0; a < 8; a++)
#pragma unroll
    for (int b = 0; b < 4; b++) acc[a][b] = zero;

  for (int t = 0; t < NKT1; ++t) {
    int cur = t & 1;
    const short* La = ldsA[cur];
    const short* Lb = ldsB[cur];
    int kts = (t + 2) * 64;
    bool st = (t + 2) < NKT1;
    bool steady = t < (NKT1 - 2);
    bf16x8 af[4][2], bf0[2][2], bf1[2][2];
    // ---- P1: reads af0+bf0; MFMA Q0 (rt0-3 x ct0-1) ----
#pragma unroll
    for (int rt = 0; rt < 4; rt++) {
      int ro = (arowbase + rt * 16) * 64;
      af[rt][0] = *(const bf16x8*)(La + ro + offk0);
      af[rt][1] = *(const bf16x8*)(La + ro + offk1);
    }
#pragma unroll
    for (int c = 0; c < 2; c++) {
      int ro = (browbase + c * 16) * 64;
      bf0[c][0] = *(const bf16x8*)(Lb + ro + offk0);
      bf0[c][1] = *(const bf16x8*)(Lb + ro + offk1);
    }
    bar();
    lgkm0();
    __builtin_amdgcn_s_setprio(1);
#pragma unroll
    for (int kk = 0; kk < 2; kk++)
#pragma unroll
      for (int rt = 0; rt < 4; rt++)
#pragma unroll
        for (int c = 0; c < 2; c++)
          acc[rt][c] = __builtin_amdgcn_mfma_f32_16x16x32_bf16(bf0[c][kk], af[rt][kk], acc[rt][c], 0, 0, 0);
    __builtin_amdgcn_s_setprio(0);
    bar();
    // ---- P2: stage A0+B0(t+2); reads bf1; MFMA Q1 (rt0-3 x ct2-3) ----
    if (st) {
      GLL(aptr[0] + kts,    &ldsA[cur][ldsa_base[0]]);
      GLL(aptr[2] + kts,    &ldsA[cur][ldsa_base[2]]);
      GLL(bptr[0][0] + kts, &ldsB[cur][ldsb_base[0][0]]);
      GLL(bptr[0][1] + kts, &ldsB[cur][ldsb_base[0][1]]);
    }
#pragma unroll
    for (int c = 0; c < 2; c++) {
      int ro = (browbase + (c + 2) * 16) * 64;
      bf1[c][0] = *(const bf16x8*)(Lb + ro + offk0);
      bf1[c][1] = *(const bf16x8*)(Lb + ro + offk1);
    }
    bar();
    lgkm0();
    __builtin_amdgcn_s_setprio(1);
#pragma unroll
    for (int kk = 0; kk < 2; kk++)
#pragma unroll
      for (int rt = 0; rt < 4; rt++)
#pragma unroll
        for (int c = 0; c < 2; c++)
          acc[rt][c + 2] = __builtin_amdgcn_mfma_f32_16x16x32_bf16(bf1[c][kk], af[rt][kk], acc[rt][c + 2], 0, 0, 0);
    __builtin_amdgcn_s_setprio(0);
    bar();
    // ---- P3: stage B1(t+2); reads af1; MFMA Q2 (rt4-7 x ct0-1) ----
    if (st) {
      GLL(bptr[1][0] + kts, &ldsB[cur][ldsb_base[1][0]]);
      GLL(bptr[1][1] + kts, &ldsB[cur][ldsb_base[1][1]]);
    }
#pragma unroll
    for (int rt = 0; rt < 4; rt++) {
      int ro = (arowbase + 64 + rt * 16) * 64;
      af[rt][0] = *(const bf16x8*)(La + ro + offk0);
      af[rt][1] = *(const bf16x8*)(La + ro + offk1);
    }
    bar();
    lgkm0();
    __builtin_amdgcn_s_setprio(1);
#pragma unroll
    for (int kk = 0; kk < 2; kk++)
#pragma unroll
      for (int rt = 0; rt < 4; rt++)
#pragma unroll
        for (int c = 0; c < 2; c++)
          acc[4 + rt][c] = __builtin_amdgcn_mfma_f32_16x16x32_bf16(bf0[c][kk], af[rt][kk], acc[4 + rt][c], 0, 0, 0);
    __builtin_amdgcn_s_setprio(0);
    bar();
    // ---- P4: stage A1(t+2); MFMA Q3 (rt4-7 x ct2-3); vmcnt once/tile ----
    if (st) {
      GLL(aptr[1] + kts,    &ldsA[cur][ldsa_base[1]]);
      GLL(aptr[3] + kts,    &ldsA[cur][ldsa_base[3]]);
    }
    bar();
    lgkm0();
    __builtin_amdgcn_s_setprio(1);
#pragma unroll
    for (int kk = 0; kk < 2; kk++)
#pragma unroll
      for (int rt = 0; rt < 4; rt++)
#pragma unroll
        for (int c = 0; c < 2; c++)
          acc[4 + rt][c + 2] = __builtin_amdgcn_mfma_f32_16x16x32_bf16(bf1[c][kk], af[rt][kk], acc[4 + rt][c + 2], 0, 0, 0);
    __builtin_amdgcn_s_setprio(0);
    if (steady) vm_bar8(); else vm_bar0();
  }

  // epilogue: gelu + bias -> bf16 pack -> 8B stores
#pragma unroll
  for (int rt = 0; rt < 8; rt++) {
    int caprow = bm * 256 + wm * 128 + rt * 16 + ln;
    size_t rowoff = ((size_t)bz * CAP + caprow) * HDIM;
#pragma unroll
    for (int c = 0; c < 4; c++) {
      int colb = bn * 256 + wn * 64 + c * 16 + q4 * 4;
      float4 bias = *(const float4*)(b1 + (size_t)e_abs * HDIM + colb);
      unsigned u0 = bfbits(gelu_f(acc[rt][c][0] + bias.x));
      unsigned u1 = bfbits(gelu_f(acc[rt][c][1] + bias.y));
      unsigned u2 = bfbits(gelu_f(acc[rt][c][2] + bias.z));
      unsigned u3 = bfbits(gelu_f(acc[rt][c][3] + bias.w));
      uint2 pk;
      pk.x = __builtin_amdgcn_perm(u1, u0, 0x07060302u);
      pk.y = __builtin_amdgcn_perm(u3, u2, 0x07060302u);
      *(uint2*)(Hh + rowoff + colb) = pk;
    }
  }
}

// ---------------- GEMM2: 128x256xBK64, 8 waves, 2-phase (2 barriers/phase); fused combine ----------------
// A = Hh [cap][H] (dense), B = W2t [M][H]. Per-wave out = 64(cap) x 64(M).
// Reads: P1: af0(4)+bf(8); P2: af1(4).  Stages: P1: A1(t+1)->buf[cur^1]; P2: A0,B(t+2)->buf[cur].
// Ledger (FIFO, per wave): end-P1 outstanding 6 (A0B t+1 + A1 t+1), needs A1(t) -> vmcnt(6);
// end-P2 outstanding 6 (A1 t+1 + A0B t+2), needs A0B(t+1) -> vmcnt(6). Tail drains vmcnt(0).
__global__ __launch_bounds__(512, 2) void gemm2_kernel(
    const short* __restrict__ Hh, const short* __restrict__ W2t,
    const float* __restrict__ b2, const int* __restrict__ s2t,
    const float* __restrict__ gate, float* __restrict__ out, int eg) {
  __shared__ __align__(16) short ldsA[2][128 * 64];
  __shared__ __align__(16) short ldsB[2][256 * 64];
  int bz = blockIdx.z, bm = blockIdx.y, bn = blockIdx.x;
  int e_abs = eg + bz;
  int tid = threadIdx.x, lane = tid & 63, w = tid >> 6;
  int v = tid >> 3, sl = tid & 7;
  const short* Ae = Hh + ((size_t)bz * CAP + (size_t)bm * 128) * HDIM;
  const short* Be = W2t + ((size_t)e_abs * MDIM + (size_t)bn * 256) * HDIM;
  const short* aptr[2];
#pragma unroll
  for (int h = 0; h < 2; h++) {
    int r = (v >> 5) * 64 + (v & 31) + h * 32;   // 32-row interleave: half h = P(h+1)'s rows
    aptr[h] = Ae + (size_t)r * HDIM + ((sl ^ (r & 7)) * 8);
  }
  const short* bptr[4];
#pragma unroll
  for (int q = 0; q < 4; q++) {
    int r = q * 64 + v;
    bptr[q] = Be + (size_t)r * HDIM + ((sl ^ (r & 7)) * 8);
  }
  int ldsa_base[2], ldsb_base[4];
#pragma unroll
  for (int h = 0; h < 2; h++) ldsa_base[h] = (h * 32 + (w >> 2) * 64 + (w & 3) * 8) * 64;
#pragma unroll
  for (int q = 0; q < 4; q++) ldsb_base[q] = (q * 64 + w * 8) * 64;

  // prologue: A0(0), B(0), A1(0), A0(1), B(1)  -> wait oldest 6 (tile 0)
  GLL(aptr[0] + 0,  &ldsA[0][ldsa_base[0]]);
  GLL(bptr[0] + 0,  &ldsB[0][ldsb_base[0]]);
  GLL(bptr[1] + 0,  &ldsB[0][ldsb_base[1]]);
  GLL(bptr[2] + 0,  &ldsB[0][ldsb_base[2]]);
  GLL(bptr[3] + 0,  &ldsB[0][ldsb_base[3]]);
  GLL(aptr[1] + 0,  &ldsA[0][ldsa_base[1]]);
  GLL(aptr[0] + 64, &ldsA[1][ldsa_base[0]]);
  GLL(bptr[0] + 64, &ldsB[1][ldsb_base[0]]);
  GLL(bptr[1] + 64, &ldsB[1][ldsb_base[1]]);
  GLL(bptr[2] + 64, &ldsB[1][ldsb_base[2]]);
  GLL(bptr[3] + 64, &ldsB[1][ldsb_base[3]]);
  asm volatile("s_waitcnt vmcnt(5)" ::: "memory");
  __builtin_amdgcn_s_barrier();
  asm volatile("" ::: "memory");

  int wm = w >> 2, wn = w & 3;
  int ln = lane & 15, q4 = lane >> 4;
  int offk0 = ((q4 ^ (lane & 7)) * 8);
  int offk1 = (((4 + q4) ^ (lane & 7)) * 8);
  int arowbase = wm * 64 + ln;
  int browbase = wn * 64 + ln;

  f32x4 acc[4][4];
  f32x4 zero = {0.f, 0.f, 0.f, 0.f};
#pragma unroll
  for (int a = 0; a < 4; a++)
#pragma unroll
    for (int b = 0; b < 4; b++) acc[a][b] = zero;

  for (int t = 0; t < NKT2; ++t) {
    int cur = t & 1;
    const short* La = ldsA[cur];
    const short* Lb = ldsB[cur];
    bool steady = t < (NKT2 - 2);
    bf16x8 af[2][2], bf[4][2];
    // ---- P1: stage A1(t+1); reads af0+bf(all); MFMA rt0-1 x ct0-3 ----
    if (t + 1 < NKT2) { GLL(aptr[1] + (t + 1) * 64, &ldsA[cur ^ 1][ldsa_base[1]]); }
#pragma unroll
    for (int rt = 0; rt < 2; rt++) {
      int ro = (arowbase + rt * 16) * 64;
      af[rt][0] = *(const bf16x8*)(La + ro + offk0);
      af[rt][1] = *(const bf16x8*)(La + ro + offk1);
    }
#pragma unroll
    for (int c = 0; c < 4; c++) {
      int ro = (browbase + c * 16) * 64;
      bf[c][0] = *(const bf16x8*)(Lb + ro + offk0);
      bf[c][1] = *(const bf16x8*)(Lb + ro + offk1);
    }
    bar();
    lgkm0();
    __builtin_amdgcn_s_setprio(1);
#pragma unroll
    for (int kk = 0; kk < 2; kk++)
#pragma unroll
      for (int rt = 0; rt < 2; rt++)
#pragma unroll
        for (int c = 0; c < 4; c++)
          acc[rt][c] = __builtin_amdgcn_mfma_f32_16x16x32_bf16(bf[c][kk], af[rt][kk], acc[rt][c], 0, 0, 0);
    __builtin_amdgcn_s_setprio(0);
    if (steady) vm_bar6(); else vm_bar0();
    // ---- P2: stage A0+B(t+2); reads af1; MFMA rt2-3 x ct0-3 ----
    if (t + 2 < NKT2) {
      int kts = (t + 2) * 64;
      GLL(aptr[0] + kts, &ldsA[cur][ldsa_base[0]]);
      GLL(bptr[0] + kts, &ldsB[cur][ldsb_base[0]]);
      GLL(bptr[1] + kts, &ldsB[cur][ldsb_base[1]]);
      GLL(bptr[2] + kts, &ldsB[cur][ldsb_base[2]]);
      GLL(bptr[3] + kts, &ldsB[cur][ldsb_base[3]]);
    }
#pragma unroll
    for (int rt = 0; rt < 2; rt++) {
      int ro = (arowbase + 32 + rt * 16) * 64;
      af[rt][0] = *(const bf16x8*)(La + ro + offk0);
      af[rt][1] = *(const bf16x8*)(La + ro + offk1);
    }
    bar();
    lgkm0();
    __builtin_amdgcn_s_setprio(1);
#pragma unroll
    for (int kk = 0; kk < 2; kk++)
#pragma unroll
      for (int rt = 0; rt < 2; rt++)
#pragma unroll
        for (int c = 0; c < 4; c++)
          acc[2 + rt][c] = __builtin_amdgcn_mfma_f32_16x16x32_bf16(bf[c][kk], af[rt][kk], acc[2 + rt][c], 0, 0, 0);
    __builtin_amdgcn_s_setprio(0);
    if (steady) vm_bar6(); else vm_bar0();
  }

  // epilogue: bias + gate scale, scatter to token rows
#pragma unroll
  for (int rt = 0; rt < 4; rt++) {
    int caprow = bm * 128 + wm * 64 + rt * 16 + ln;
    int token = s2t[e_abs * CAP + caprow];
    if (token < 0) continue;
    float g = gate[token];
    float* orow = out + (size_t)token * MDIM;
#pragma unroll
    for (int c = 0; c < 4; c++) {
      int colb = bn * 256 + wn * 64 + c * 16 + q4 * 4;
      float4 bias = *(const float4*)(b2 + (size_t)e_abs * MDIM + colb);
      float4 vv;
      vv.x = (acc[rt][c][0] + bias.x) * g;
      vv.y = (acc[rt][c][1] + bias.y) * g;
      vv.z = (acc[rt][c][2] + bias.z) * g;
      vv.w = (acc[rt][c][3] + bias.w) * g;
      *(float4*)(orow + colb) = vv;
    }
  }
}

// ---------------- zero rows of dropped tokens ----------------
__global__ __launch_bounds__(256) void zerodrop_kernel(
    const float* __restrict__ gate, float* __restrict__ out) {
  int t = blockIdx.x;
  if (gate[t] != 0.f) return;
  float4 z = {0.f, 0.f, 0.f, 0.f};
  ((float4*)(out + (size_t)t * MDIM))[threadIdx.x] = z;
}

extern "C" void kernel_launch(void* const* d_in, const int* in_sizes, int n_in,
                              void* d_out, int out_size, void* d_ws, size_t ws_size,
                              hipStream_t stream) {
  const float* x  = (const float*)d_in[0];
  const float* wg = (const float*)d_in[1];
  const float* w1 = (const float*)d_in[2];
  const float* b1 = (const float*)d_in[3];
  const float* w2 = (const float*)d_in[4];
  const float* b2 = (const float*)d_in[5];
  float* out = (float*)d_out;

  char* ws = (char*)d_ws;
  size_t off = 0;
  auto alloc = [&](size_t n) { char* ptr = ws + off; off += (n + 255) & ~(size_t)255; return ptr; };
  short* W1t  = (short*)alloc((size_t)NEXP * MDIM * HDIM * 2);   // 67 MB [E][H][M]
  short* W2t  = (short*)alloc((size_t)NEXP * MDIM * HDIM * 2);   // 67 MB [E][M][H]
  short* Hh   = (short*)alloc((size_t)EGRP * CAP * HDIM * 2);    // 67 MB (4 experts, full H)
  short* xb   = (short*)alloc((size_t)TOKENS * MDIM * 2);        // 33.5 MB bf16 x
  short* zrow = (short*)alloc((size_t)MDIM * 2);
  int*   idx  = (int*)  alloc(TOKENS * 4);
  float* gate = (float*)alloc(TOKENS * 4);
  int*   s2t  = (int*)  alloc(NEXP * CAP * 4);
  float* mep  = (float*)alloc((TOKENS / 4) * NEXP * 4);
  int*   cnts = (int*)  alloc(NEXP * 4);
  if (ws_size < off) return;

  hipMemsetAsync(s2t, 0xFF, NEXP * CAP * 4, stream);  // -1 sentinels
  hipMemsetAsync(zrow, 0, MDIM * 2, stream);

  gating_kernel<<<TOKENS / 4, 256, 0, stream>>>(x, wg, idx, gate, mep, xb);
  scan_kernel<<<1, 1024, 0, stream>>>(idx, gate, s2t, cnts, mep, out + (size_t)TOKENS * MDIM);
  transpose_cvt_kernel<<<dim3(HDIM / 64, MDIM / 64, NEXP), 256, 0, stream>>>(w1, W1t, MDIM, HDIM);
  transpose_cvt_kernel<<<dim3(MDIM / 64, HDIM / 64, NEXP), 256, 0, stream>>>(w2, W2t, HDIM, MDIM);
  for (int g = 0; g < 2; g++) {
    gemm1_kernel<<<dim3(HDIM / 256, CAP / 256, EGRP), 512, 0, stream>>>(xb, s2t, W1t, b1, Hh, zrow, g * EGRP);
    gemm2_kernel<<<dim3(MDIM / 256, CAP / 128, EGRP), 512, 0, stream>>>(Hh, W2t, b2, s2t, gate, out, g * EGRP);
  }
  zerodrop_kernel<<<TOKENS, 256, 0, stream>>>(gate, out);
}

// Round 3
// 888.339 us; speedup vs baseline: 1.0506x; 1.0506x over previous
//
#include <hip/hip_runtime.h>
#include <hip/hip_bf16.h>

#define TOKENS 16384
#define MDIM   1024
#define HDIM   4096
#define NEXP   8
#define EGRP   4          // experts per GEMM group (2 groups)
#define CAP    2048
#define NKT1   (MDIM / 64)   // 16 K-tiles for GEMM1
#define NKT2   (HDIM / 64)   // 64 K-tiles for GEMM2

typedef __attribute__((ext_vector_type(8))) short bf16x8;  // 8 bf16 = 4 VGPR
typedef __attribute__((ext_vector_type(4))) float f32x4;

__device__ __forceinline__ short f2bf(float x) {
  unsigned u = __float_as_uint(x);
  unsigned r = (u + 0x7fffu + ((u >> 16) & 1u)) >> 16;
  return (short)r;
}

// round bits to bf16 boundary (RNE), result in high 16 bits
__device__ __forceinline__ unsigned bfbits(float x) {
  unsigned u = __float_as_uint(x);
  return u + 0x7fffu + ((u >> 16) & 1u);
}

__device__ __forceinline__ float gelu_f(float x) {
  // jax.nn.gelu approximate=True
  float u = 1.5957691216057308f * (x + 0.044715f * x * x * x);
  float e = __expf(u);
  return x * (1.f - 1.f / (e + 1.f));
}

// ---------------- gating: logits -> softmax -> argmax; also emit bf16 x ----------------
__global__ __launch_bounds__(256) void gating_kernel(
    const float* __restrict__ x, const float* __restrict__ wg,
    int* __restrict__ idx, float* __restrict__ gate,
    float* __restrict__ mepart, short* __restrict__ xb) {
  __shared__ float me_s[NEXP];
  int tid = threadIdx.x, wid = tid >> 6, lane = tid & 63;
  if (tid < NEXP) me_s[tid] = 0.f;
  __syncthreads();
  int t = blockIdx.x * 4 + wid;
  float acc[NEXP];
#pragma unroll
  for (int e = 0; e < NEXP; e++) acc[e] = 0.f;
  const float4* xr = (const float4*)(x + (size_t)t * MDIM);
  short* xbr = xb + (size_t)t * MDIM + lane * 16;
#pragma unroll
  for (int j = 0; j < 4; j++) {
    float4 xv = xr[lane * 4 + j];
    short4 bv; bv.x = f2bf(xv.x); bv.y = f2bf(xv.y); bv.z = f2bf(xv.z); bv.w = f2bf(xv.w);
    ((short4*)(xbr))[j] = bv;
    int base = lane * 16 + j * 4;
    const float* xp = &xv.x;
#pragma unroll
    for (int i = 0; i < 4; i++) {
      float xi = xp[i];
      const float4* wr = (const float4*)(wg + (size_t)(base + i) * NEXP);
      float4 w0 = wr[0], w1 = wr[1];
      acc[0] += xi * w0.x; acc[1] += xi * w0.y; acc[2] += xi * w0.z; acc[3] += xi * w0.w;
      acc[4] += xi * w1.x; acc[5] += xi * w1.y; acc[6] += xi * w1.z; acc[7] += xi * w1.w;
    }
  }
#pragma unroll
  for (int off = 32; off > 0; off >>= 1)
#pragma unroll
    for (int e = 0; e < NEXP; e++) acc[e] += __shfl_xor(acc[e], off, 64);
  if (lane == 0) {
    float mx = acc[0]; int ai = 0;
#pragma unroll
    for (int e = 1; e < NEXP; e++) if (acc[e] > mx) { mx = acc[e]; ai = e; }
    float ex[NEXP]; float se = 0.f;
#pragma unroll
    for (int e = 0; e < NEXP; e++) { ex[e] = __expf(acc[e] - mx); se += ex[e]; }
    float inv = 1.f / se;
#pragma unroll
    for (int e = 0; e < NEXP; e++) atomicAdd(&me_s[e], ex[e] * inv);
    idx[t] = ai;
    gate[t] = inv;
  }
  __syncthreads();
  if (tid < NEXP) mepart[blockIdx.x * NEXP + tid] = me_s[tid];
}

// ---------------- ordered scan: queue positions + l_aux tail ----------------
__global__ __launch_bounds__(1024) void scan_kernel(
    const int* __restrict__ idx, float* __restrict__ gate,
    int* __restrict__ s2t, int* __restrict__ counts,
    const float* __restrict__ mepart, float* __restrict__ out_tail) {
  __shared__ int wcnt[16][NEXP];
  __shared__ int wbase[16][NEXP];
  __shared__ int totc[NEXP];
  __shared__ float red2[1024];
  int tid = threadIdx.x, wid = tid >> 6, lane = tid & 63;
  unsigned long long ltmask = (1ull << lane) - 1ull;
  int myexp[16], myloc[16];
  int cnt[NEXP];
#pragma unroll
  for (int e = 0; e < NEXP; e++) cnt[e] = 0;
  int base_tok = wid * 1024;
#pragma unroll
  for (int p = 0; p < 16; p++) {
    int e = idx[base_tok + p * 64 + lane];
    myexp[p] = e;
    int pos = 0;
#pragma unroll
    for (int e2 = 0; e2 < NEXP; e2++) {
      unsigned long long b = __ballot(e == e2);
      if (e == e2) pos = cnt[e2] + __popcll(b & ltmask);
      cnt[e2] += __popcll(b);            // wave-uniform
    }
    myloc[p] = pos;
  }
  if (lane < NEXP) wcnt[wid][lane] = cnt[lane];
  __syncthreads();
  if (tid < 128) {
    int w = tid >> 3, e = tid & 7;
    int s = 0;
    for (int w2 = 0; w2 < w; w2++) s += wcnt[w2][e];
    wbase[w][e] = s;
  }
  __syncthreads();
#pragma unroll
  for (int p = 0; p < 16; p++) {
    int i = base_tok + p * 64 + lane;
    int e = myexp[p];
    int loc = wbase[wid][e] + myloc[p];
    if (loc < CAP) s2t[e * CAP + loc] = i;
    else           gate[i] = 0.f;
  }
  if (tid < NEXP) {
    int tot = 0;
#pragma unroll
    for (int w = 0; w < 16; w++) tot += wcnt[w][tid];
    counts[tid] = tot;
    totc[tid] = tot;
  }
  // ---- l_aux + exp_counts tail (absorbed finalize_kernel) ----
  float s = 0.f;
  int e2 = tid & 7;
  for (int r = tid >> 3; r < (TOKENS / 4); r += 128) s += mepart[(size_t)r * NEXP + e2];
  red2[tid] = s;
  __syncthreads();
#pragma unroll
  for (int off = 512; off >= 8; off >>= 1) {
    if (tid < off) red2[tid] += red2[tid + off];
    __syncthreads();
  }
  if (tid == 0) {
    float la = 0.f;
    for (int k = 0; k < NEXP; k++)
      la += (red2[k] / (float)TOKENS) * ((float)totc[k] / (float)TOKENS);
    out_tail[0] = la * (float)NEXP;
  }
  if (tid < NEXP) out_tail[1 + tid] = (float)totc[tid];
}

// ---------------- fp32 [E][R][C] -> bf16 [E][C][R], 64x64 LDS tiles ----------------
__global__ __launch_bounds__(256) void transpose_cvt_kernel(
    const float* __restrict__ in, short* __restrict__ out, int R, int Cc) {
  __shared__ short tile[64][72];   // pad 72: 8B-aligned b64 reads, <=2-way banks
  int e = blockIdx.z;
  const float* in_e = in + (size_t)e * R * Cc;
  short* out_e = out + (size_t)e * R * Cc;
  int r0 = blockIdx.y * 64, c0 = blockIdx.x * 64;
  int tid = threadIdx.x;
#pragma unroll
  for (int i = 0; i < 4; i++) {
    int linear = tid + 256 * i;          // 0..1023
    int r = linear >> 4;                 // 0..63
    int f4 = linear & 15;                // 0..15
    float4 v = *(const float4*)(in_e + (size_t)(r0 + r) * Cc + c0 + f4 * 4);
    int c = f4 * 4;
    tile[c + 0][r] = f2bf(v.x);
    tile[c + 1][r] = f2bf(v.y);
    tile[c + 2][r] = f2bf(v.z);
    tile[c + 3][r] = f2bf(v.w);
  }
  __syncthreads();
#pragma unroll
  for (int i = 0; i < 4; i++) {
    int linear = tid + 256 * i;
    int c = linear >> 4;
    int s4 = linear & 15;
    short4 s;
    s.x = tile[c][s4 * 4 + 0]; s.y = tile[c][s4 * 4 + 1];
    s.z = tile[c][s4 * 4 + 2]; s.w = tile[c][s4 * 4 + 3];
    *(short4*)(out_e + (size_t)(c0 + c) * R + r0 + s4 * 4) = s;
  }
}

// ---------------- pipeline phase boundaries (counted vmcnt + raw barrier) ----------------
// vmcnt BEFORE barrier: each wave guarantees its own staged loads landed, then all
// waves sync -> LDS tile globally ready. Counted (never 0) in steady state.
__device__ __forceinline__ void vm_bar8() {
  asm volatile("s_waitcnt vmcnt(8)" ::: "memory");
  __builtin_amdgcn_s_barrier();
  asm volatile("" ::: "memory");
}
__device__ __forceinline__ void vm_bar4() {
  asm volatile("s_waitcnt vmcnt(4)" ::: "memory");
  __builtin_amdgcn_s_barrier();
  asm volatile("" ::: "memory");
}
__device__ __forceinline__ void vm_bar0() {
  asm volatile("s_waitcnt vmcnt(0)" ::: "memory");
  __builtin_amdgcn_s_barrier();
  asm volatile("" ::: "memory");
}

#define GLL(gp, lp) __builtin_amdgcn_global_load_lds(                                   \
    (const __attribute__((address_space(1))) void*)(gp),                                \
    (__attribute__((address_space(3))) void*)(lp), 16, 0, 0)

// ---------------- GEMM1: 256x256xBK64, 8 waves, 2 phases/K-tile (2 barriers) ----------------
// A = gathered xb rows (cap dim), B = W1t [H][M]. MFMA operands swapped:
// D[col=lane&15 -> cap row][row=(lane>>4)*4+j -> H col].
// LDS swizzle: LDS(r, s) = G(r, s ^ (r&7)) at 8-short granularity.
// P_a(t): GLL A1(t+1)->buf[cur^1]; read af0(8)+bf(8); 32 MFMA (rt0-3 x c0-3); vm_bar8.
// P_b(t): GLL A0+B(t+2)->buf[cur];  read af1(8);       32 MFMA (rt4-7 x c0-3, held bf); vm_bar8.
// FIFO ledger: end-P_a leaves {A0B(t+1)6, A1(t+1)2}; end-P_b leaves {A1(t+1)2, A0B(t+2)6}
// -> vmcnt(8) at both is exact. Tail (t >= NKT1-2) drains vm0.
// XCD swizzle: each XCD gets one bz x 4bm x all-bn chunk (A-panel L2 reuse).
__global__ __launch_bounds__(512, 2) void gemm1_kernel(
    const short* __restrict__ xb, const int* __restrict__ s2t,
    const short* __restrict__ W1t, const float* __restrict__ b1,
    short* __restrict__ Hh, const short* __restrict__ zrow, int eg) {
  __shared__ __align__(16) short ldsA[2][256 * 64];
  __shared__ __align__(16) short ldsB[2][256 * 64];
  int flat = blockIdx.x + 16 * blockIdx.y + 128 * blockIdx.z;   // nwg = 512
  int swz = (flat & 7) * 64 + (flat >> 3);                      // bijective (512 % 8 == 0)
  int bn = swz & 15, bm = (swz >> 4) & 7, bz = swz >> 7;
  int e_abs = eg + bz;
  int tid = threadIdx.x, lane = tid & 63, w = tid >> 6;
  int v = tid >> 3;                  // 0..63: row-within-round selector
  int sl = tid & 7;                  // source 16B slot selector

  // A staging pointers (token gather), rounds q=0..3: row = q*64 + v
  const short* aptr[4];
#pragma unroll
  for (int q = 0; q < 4; q++) {
    int r = q * 64 + v;
    int tok = s2t[e_abs * CAP + bm * 256 + r];
    const short* basep = (tok >= 0) ? (xb + (size_t)tok * MDIM) : zrow;
    aptr[q] = basep + ((sl ^ (r & 7)) * 8);
  }
  // B staging pointers, rounds q=0..3: row = q*64 + v
  const short* Be = W1t + ((size_t)e_abs * HDIM + (size_t)bn * 256) * MDIM;
  const short* bptr[4];
#pragma unroll
  for (int q = 0; q < 4; q++) {
    int r = q * 64 + v;
    bptr[q] = Be + (size_t)r * MDIM + ((sl ^ (r & 7)) * 8);
  }
  asm volatile("" ::: "memory");   // pin gather loads before first stage

  // wave-uniform LDS destination bases (shorts)
  int ldsa_base[4], ldsb_base[4];
#pragma unroll
  for (int q = 0; q < 4; q++) { ldsa_base[q] = (q * 64 + w * 8) * 64; ldsb_base[q] = (q * 64 + w * 8) * 64; }

  // prologue: A0(0)2, B(0)4, A1(0)2, A0(1)2, B(1)4  (A1(1) staged by P_a(0))
  GLL(aptr[0] + 0,  &ldsA[0][ldsa_base[0]]);
  GLL(aptr[2] + 0,  &ldsA[0][ldsa_base[2]]);
  GLL(bptr[0] + 0,  &ldsB[0][ldsb_base[0]]);
  GLL(bptr[1] + 0,  &ldsB[0][ldsb_base[1]]);
  GLL(bptr[2] + 0,  &ldsB[0][ldsb_base[2]]);
  GLL(bptr[3] + 0,  &ldsB[0][ldsb_base[3]]);
  GLL(aptr[1] + 0,  &ldsA[0][ldsa_base[1]]);
  GLL(aptr[3] + 0,  &ldsA[0][ldsa_base[3]]);
  GLL(aptr[0] + 64, &ldsA[1][ldsa_base[0]]);
  GLL(aptr[2] + 64, &ldsA[1][ldsa_base[2]]);
  GLL(bptr[0] + 64, &ldsB[1][ldsb_base[0]]);
  GLL(bptr[1] + 64, &ldsB[1][ldsb_base[1]]);
  GLL(bptr[2] + 64, &ldsB[1][ldsb_base[2]]);
  GLL(bptr[3] + 64, &ldsB[1][ldsb_base[3]]);
  vm_bar8();                         // A0(0)+B(0) landed; rest in flight

  int wm = w >> 2, wn = w & 3;       // 2 x 4 wave grid; per-wave out = 128(cap) x 64(H)
  int ln = lane & 15, q4 = lane >> 4;
  int offk0 = ((q4 ^ (lane & 7)) * 8);
  int offk1 = (((4 + q4) ^ (lane & 7)) * 8);
  int arowbase = wm * 128 + ln;
  int browbase = wn * 64 + ln;

  f32x4 acc[8][4];
  f32x4 zero = {0.f, 0.f, 0.f, 0.f};
#pragma unroll
  for (int a = 0; a < 8; a++)
#pragma unroll
    for (int b = 0; b < 4; b++) acc[a][b] = zero;

  for (int t = 0; t < NKT1; ++t) {
    int cur = t & 1;
    const short* La = ldsA[cur];
    const short* Lb = ldsB[cur];
    bool steady = t < (NKT1 - 2);
    bf16x8 af[4][2], bfr[4][2];
    // ---- P_a: GLL A1(t+1); read af0 + all bf; 32 MFMA ----
    if (t + 1 < NKT1) {
      int k1 = (t + 1) * 64;
      GLL(aptr[1] + k1, &ldsA[cur ^ 1][ldsa_base[1]]);
      GLL(aptr[3] + k1, &ldsA[cur ^ 1][ldsa_base[3]]);
    }
#pragma unroll
    for (int rt = 0; rt < 4; rt++) {
      int ro = (arowbase + rt * 16) * 64;
      af[rt][0] = *(const bf16x8*)(La + ro + offk0);
      af[rt][1] = *(const bf16x8*)(La + ro + offk1);
    }
#pragma unroll
    for (int c = 0; c < 4; c++) {
      int ro = (browbase + c * 16) * 64;
      bfr[c][0] = *(const bf16x8*)(Lb + ro + offk0);
      bfr[c][1] = *(const bf16x8*)(Lb + ro + offk1);
    }
    __builtin_amdgcn_s_setprio(1);
#pragma unroll
    for (int rt = 0; rt < 4; rt++)
#pragma unroll
      for (int c = 0; c < 4; c++) {
        acc[rt][c] = __builtin_amdgcn_mfma_f32_16x16x32_bf16(bfr[c][0], af[rt][0], acc[rt][c], 0, 0, 0);
        acc[rt][c] = __builtin_amdgcn_mfma_f32_16x16x32_bf16(bfr[c][1], af[rt][1], acc[rt][c], 0, 0, 0);
      }
    __builtin_amdgcn_s_setprio(0);
    if (steady) vm_bar8(); else vm_bar0();
    // ---- P_b: GLL A0+B(t+2); read af1; 32 MFMA (held bfr) ----
    if (t + 2 < NKT1) {
      int kts = (t + 2) * 64;
      GLL(aptr[0] + kts, &ldsA[cur][ldsa_base[0]]);
      GLL(aptr[2] + kts, &ldsA[cur][ldsa_base[2]]);
      GLL(bptr[0] + kts, &ldsB[cur][ldsb_base[0]]);
      GLL(bptr[1] + kts, &ldsB[cur][ldsb_base[1]]);
      GLL(bptr[2] + kts, &ldsB[cur][ldsb_base[2]]);
      GLL(bptr[3] + kts, &ldsB[cur][ldsb_base[3]]);
    }
#pragma unroll
    for (int rt = 0; rt < 4; rt++) {
      int ro = (arowbase + 64 + rt * 16) * 64;
      af[rt][0] = *(const bf16x8*)(La + ro + offk0);
      af[rt][1] = *(const bf16x8*)(La + ro + offk1);
    }
    __builtin_amdgcn_s_setprio(1);
#pragma unroll
    for (int rt = 0; rt < 4; rt++)
#pragma unroll
      for (int c = 0; c < 4; c++) {
        acc[4 + rt][c] = __builtin_amdgcn_mfma_f32_16x16x32_bf16(bfr[c][0], af[rt][0], acc[4 + rt][c], 0, 0, 0);
        acc[4 + rt][c] = __builtin_amdgcn_mfma_f32_16x16x32_bf16(bfr[c][1], af[rt][1], acc[4 + rt][c], 0, 0, 0);
      }
    __builtin_amdgcn_s_setprio(0);
    if (steady) vm_bar8(); else vm_bar0();
  }

  // epilogue: gelu + bias -> bf16 pack -> 8B stores
#pragma unroll
  for (int rt = 0; rt < 8; rt++) {
    int caprow = bm * 256 + wm * 128 + rt * 16 + ln;
    size_t rowoff = ((size_t)bz * CAP + caprow) * HDIM;
#pragma unroll
    for (int c = 0; c < 4; c++) {
      int colb = bn * 256 + wn * 64 + c * 16 + q4 * 4;
      float4 bias = *(const float4*)(b1 + (size_t)e_abs * HDIM + colb);
      unsigned u0 = bfbits(gelu_f(acc[rt][c][0] + bias.x));
      unsigned u1 = bfbits(gelu_f(acc[rt][c][1] + bias.y));
      unsigned u2 = bfbits(gelu_f(acc[rt][c][2] + bias.z));
      unsigned u3 = bfbits(gelu_f(acc[rt][c][3] + bias.w));
      uint2 pk;
      pk.x = __builtin_amdgcn_perm(u1, u0, 0x07060302u);
      pk.y = __builtin_amdgcn_perm(u3, u2, 0x07060302u);
      *(uint2*)(Hh + rowoff + colb) = pk;
    }
  }
}

// ---------------- GEMM2: 128x256xBK64, 8 waves, 1 barrier/K-tile; fused combine ----------------
// A = Hh [cap][H] (dense, 2-deep LDS), B = W2t [M][H] (3-deep LDS).
// Region(t): GLL A(t+1)->A[(t+1)&1], B(t+2)->B[(t-1)%3]; read all 16 b128; 32 MFMA; vm_bar4.
// FIFO ledger: end-region leaves {B(t+1)4 [old], A(t+1)2, B(t+2)4} = 10 outstanding;
// vmcnt(4) leaves only B(t+2) -> A(t+1),B(t+1) landed. Tail (t >= NKT2-2) vm0.
// Overwrite hazards: A(t+1) hits A(t-1) rows (read region t-1, barrier-separated);
// B(t+2) hits B(t-1) buffer (read region t-1, barrier-separated).
__global__ __launch_bounds__(512, 2) void gemm2_kernel(
    const short* __restrict__ Hh, const short* __restrict__ W2t,
    const float* __restrict__ b2, const int* __restrict__ s2t,
    const float* __restrict__ gate, float* __restrict__ out, int eg) {
  __shared__ __align__(16) short ldsA[2][128 * 64];
  __shared__ __align__(16) short ldsB[3][256 * 64];
  int flat = blockIdx.x + 4 * blockIdx.y + 64 * blockIdx.z;     // nwg = 256
  int swz = (flat & 7) * 32 + (flat >> 3);                      // bijective (256 % 8 == 0)
  int bn = swz & 3, bm = (swz >> 2) & 15, bz = swz >> 6;
  int e_abs = eg + bz;
  int tid = threadIdx.x, lane = tid & 63, w = tid >> 6;
  int v = tid >> 3, sl = tid & 7;
  const short* Ae = Hh + ((size_t)bz * CAP + (size_t)bm * 128) * HDIM;
  const short* Be = W2t + ((size_t)e_abs * MDIM + (size_t)bn * 256) * HDIM;
  const short* aptr[2];
#pragma unroll
  for (int h = 0; h < 2; h++) {
    int r = h * 64 + v;
    aptr[h] = Ae + (size_t)r * HDIM + ((sl ^ (r & 7)) * 8);
  }
  const short* bptr[4];
#pragma unroll
  for (int q = 0; q < 4; q++) {
    int r = q * 64 + v;
    bptr[q] = Be + (size_t)r * HDIM + ((sl ^ (r & 7)) * 8);
  }
  int ldsa_base[2], ldsb_base[4];
#pragma unroll
  for (int h = 0; h < 2; h++) ldsa_base[h] = (h * 64 + w * 8) * 64;
#pragma unroll
  for (int q = 0; q < 4; q++) ldsb_base[q] = (q * 64 + w * 8) * 64;

  // prologue: A(0)2, B(0)4, B(1)4 -> vmcnt(4): A(0),B(0) landed, B(1) in flight
  GLL(aptr[0] + 0,  &ldsA[0][ldsa_base[0]]);
  GLL(aptr[1] + 0,  &ldsA[0][ldsa_base[1]]);
  GLL(bptr[0] + 0,  &ldsB[0][ldsb_base[0]]);
  GLL(bptr[1] + 0,  &ldsB[0][ldsb_base[1]]);
  GLL(bptr[2] + 0,  &ldsB[0][ldsb_base[2]]);
  GLL(bptr[3] + 0,  &ldsB[0][ldsb_base[3]]);
  GLL(bptr[0] + 64, &ldsB[1][ldsb_base[0]]);
  GLL(bptr[1] + 64, &ldsB[1][ldsb_base[1]]);
  GLL(bptr[2] + 64, &ldsB[1][ldsb_base[2]]);
  GLL(bptr[3] + 64, &ldsB[1][ldsb_base[3]]);
  vm_bar4();

  int wm = w >> 2, wn = w & 3;
  int ln = lane & 15, q4 = lane >> 4;
  int offk0 = ((q4 ^ (lane & 7)) * 8);
  int offk1 = (((4 + q4) ^ (lane & 7)) * 8);
  int arowbase = wm * 64 + ln;
  int browbase = wn * 64 + ln;

  f32x4 acc[4][4];
  f32x4 zero = {0.f, 0.f, 0.f, 0.f};
#pragma unroll
  for (int a = 0; a < 4; a++)
#pragma unroll
    for (int b = 0; b < 4; b++) acc[a][b] = zero;

  // rotating B buffer pointers (no runtime-indexed array -> stays in registers)
  short* b_cur = ldsB[0];
  short* b_n1  = ldsB[1];
  short* b_n2  = ldsB[2];

  for (int t = 0; t < NKT2; ++t) {
    const short* La = ldsA[t & 1];
    const short* Lb = b_cur;
    bool steady = t < (NKT2 - 2);
    // stage A(t+1) -> other A buffer; B(t+2) -> b_n2
    if (t + 1 < NKT2) {
      int k1 = (t + 1) * 64;
      GLL(aptr[0] + k1, &ldsA[(t + 1) & 1][ldsa_base[0]]);
      GLL(aptr[1] + k1, &ldsA[(t + 1) & 1][ldsa_base[1]]);
    }
    if (t + 2 < NKT2) {
      int k2 = (t + 2) * 64;
      GLL(bptr[0] + k2, b_n2 + ldsb_base[0]);
      GLL(bptr[1] + k2, b_n2 + ldsb_base[1]);
      GLL(bptr[2] + k2, b_n2 + ldsb_base[2]);
      GLL(bptr[3] + k2, b_n2 + ldsb_base[3]);
    }
    bf16x8 af[4][2], bf[4][2];
#pragma unroll
    for (int rt = 0; rt < 4; rt++) {
      int ro = (arowbase + rt * 16) * 64;
      af[rt][0] = *(const bf16x8*)(La + ro + offk0);
      af[rt][1] = *(const bf16x8*)(La + ro + offk1);
    }
#pragma unroll
    for (int c = 0; c < 4; c++) {
      int ro = (browbase + c * 16) * 64;
      bf[c][0] = *(const bf16x8*)(Lb + ro + offk0);
      bf[c][1] = *(const bf16x8*)(Lb + ro + offk1);
    }
    __builtin_amdgcn_s_setprio(1);
#pragma unroll
    for (int rt = 0; rt < 4; rt++)
#pragma unroll
      for (int c = 0; c < 4; c++) {
        acc[rt][c] = __builtin_amdgcn_mfma_f32_16x16x32_bf16(bf[c][0], af[rt][0], acc[rt][c], 0, 0, 0);
        acc[rt][c] = __builtin_amdgcn_mfma_f32_16x16x32_bf16(bf[c][1], af[rt][1], acc[rt][c], 0, 0, 0);
      }
    __builtin_amdgcn_s_setprio(0);
    if (steady) vm_bar4(); else vm_bar0();
    short* tmp = b_cur; b_cur = b_n1; b_n1 = b_n2; b_n2 = tmp;
  }

  // epilogue: bias + gate scale, scatter to token rows
#pragma unroll
  for (int rt = 0; rt < 4; rt++) {
    int caprow = bm * 128 + wm * 64 + rt * 16 + ln;
    int token = s2t[e_abs * CAP + caprow];
    if (token < 0) continue;
    float g = gate[token];
    float* orow = out + (size_t)token * MDIM;
#pragma unroll
    for (int c = 0; c < 4; c++) {
      int colb = bn * 256 + wn * 64 + c * 16 + q4 * 4;
      float4 bias = *(const float4*)(b2 + (size_t)e_abs * MDIM + colb);
      float4 vv;
      vv.x = (acc[rt][c][0] + bias.x) * g;
      vv.y = (acc[rt][c][1] + bias.y) * g;
      vv.z = (acc[rt][c][2] + bias.z) * g;
      vv.w = (acc[rt][c][3] + bias.w) * g;
      *(float4*)(orow + colb) = vv;
    }
  }
}

// ---------------- zero rows of dropped tokens ----------------
__global__ __launch_bounds__(256) void zerodrop_kernel(
    const float* __restrict__ gate, float* __restrict__ out) {
  int t = blockIdx.x;
  if (gate[t] != 0.f) return;
  float4 z = {0.f, 0.f, 0.f, 0.f};
  ((float4*)(out + (size_t)t * MDIM))[threadIdx.x] = z;
}

extern "C" void kernel_launch(void* const* d_in, const int* in_sizes, int n_in,
                              void* d_out, int out_size, void* d_ws, size_t ws_size,
                              hipStream_t stream) {
  const float* x  = (const float*)d_in[0];
  const float* wg = (const float*)d_in[1];
  const float* w1 = (const float*)d_in[2];
  const float* b1 = (const float*)d_in[3];
  const float* w2 = (const float*)d_in[4];
  const float* b2 = (const float*)d_in[5];
  float* out = (float*)d_out;

  char* ws = (char*)d_ws;
  size_t off = 0;
  auto alloc = [&](size_t n) { char* ptr = ws + off; off += (n + 255) & ~(size_t)255; return ptr; };
  short* W1t  = (short*)alloc((size_t)NEXP * MDIM * HDIM * 2);   // 67 MB [E][H][M]
  short* W2t  = (short*)alloc((size_t)NEXP * MDIM * HDIM * 2);   // 67 MB [E][M][H]
  short* Hh   = (short*)alloc((size_t)EGRP * CAP * HDIM * 2);    // 67 MB (4 experts, full H)
  short* xb   = (short*)alloc((size_t)TOKENS * MDIM * 2);        // 33.5 MB bf16 x
  short* zrow = (short*)alloc((size_t)MDIM * 2);
  int*   idx  = (int*)  alloc(TOKENS * 4);
  float* gate = (float*)alloc(TOKENS * 4);
  int*   s2t  = (int*)  alloc(NEXP * CAP * 4);
  float* mep  = (float*)alloc((TOKENS / 4) * NEXP * 4);
  int*   cnts = (int*)  alloc(NEXP * 4);
  if (ws_size < off) return;

  hipMemsetAsync(s2t, 0xFF, NEXP * CAP * 4, stream);  // -1 sentinels
  hipMemsetAsync(zrow, 0, MDIM * 2, stream);

  gating_kernel<<<TOKENS / 4, 256, 0, stream>>>(x, wg, idx, gate, mep, xb);
  scan_kernel<<<1, 1024, 0, stream>>>(idx, gate, s2t, cnts, mep, out + (size_t)TOKENS * MDIM);
  transpose_cvt_kernel<<<dim3(HDIM / 64, MDIM / 64, NEXP), 256, 0, stream>>>(w1, W1t, MDIM, HDIM);
  transpose_cvt_kernel<<<dim3(MDIM / 64, HDIM / 64, NEXP), 256, 0, stream>>>(w2, W2t, HDIM, MDIM);
  for (int g = 0; g < 2; g++) {
    gemm1_kernel<<<dim3(HDIM / 256, CAP / 256, EGRP), 512, 0, stream>>>(xb, s2t, W1t, b1, Hh, zrow, g * EGRP);
    gemm2_kernel<<<dim3(MDIM / 256, CAP / 128, EGRP), 512, 0, stream>>>(Hh, W2t, b2, s2t, gate, out, g * EGRP);
  }
  zerodrop_kernel<<<TOKENS, 256, 0, stream>>>(gate, out);
}

// Round 4
// 845.494 us; speedup vs baseline: 1.1039x; 1.0507x over previous
//
#include <hip/hip_runtime.h>
#include <hip/hip_bf16.h>

#define TOKENS 16384
#define MDIM   1024
#define HDIM   4096
#define NEXP   8
#define EGRP   4          // experts per GEMM group (2 groups)
#define CAP    2048
#define NKT1   (MDIM / 64)   // 16 K-tiles for GEMM1
#define NKT2   (HDIM / 64)   // 64 K-tiles for GEMM2

typedef __attribute__((ext_vector_type(8))) short bf16x8;  // 8 bf16 = 4 VGPR
typedef __attribute__((ext_vector_type(4))) float f32x4;

__device__ __forceinline__ short f2bf(float x) {
  unsigned u = __float_as_uint(x);
  unsigned r = (u + 0x7fffu + ((u >> 16) & 1u)) >> 16;
  return (short)r;
}

// round bits to bf16 boundary (RNE), result in high 16 bits
__device__ __forceinline__ unsigned bfbits(float x) {
  unsigned u = __float_as_uint(x);
  return u + 0x7fffu + ((u >> 16) & 1u);
}

__device__ __forceinline__ float gelu_f(float x) {
  // jax.nn.gelu approximate=True
  float u = 1.5957691216057308f * (x + 0.044715f * x * x * x);
  float e = __expf(u);
  return x * (1.f - 1.f / (e + 1.f));
}

// ---------------- gating: logits -> softmax -> argmax; also emit bf16 x ----------------
__global__ __launch_bounds__(256) void gating_kernel(
    const float* __restrict__ x, const float* __restrict__ wg,
    int* __restrict__ idx, float* __restrict__ gate,
    float* __restrict__ mepart, short* __restrict__ xb) {
  __shared__ float me_s[NEXP];
  int tid = threadIdx.x, wid = tid >> 6, lane = tid & 63;
  if (tid < NEXP) me_s[tid] = 0.f;
  __syncthreads();
  int t = blockIdx.x * 4 + wid;
  float acc[NEXP];
#pragma unroll
  for (int e = 0; e < NEXP; e++) acc[e] = 0.f;
  const float4* xr = (const float4*)(x + (size_t)t * MDIM);
  short* xbr = xb + (size_t)t * MDIM + lane * 16;
#pragma unroll
  for (int j = 0; j < 4; j++) {
    float4 xv = xr[lane * 4 + j];
    short4 bv; bv.x = f2bf(xv.x); bv.y = f2bf(xv.y); bv.z = f2bf(xv.z); bv.w = f2bf(xv.w);
    ((short4*)(xbr))[j] = bv;
    int base = lane * 16 + j * 4;
    const float* xp = &xv.x;
#pragma unroll
    for (int i = 0; i < 4; i++) {
      float xi = xp[i];
      const float4* wr = (const float4*)(wg + (size_t)(base + i) * NEXP);
      float4 w0 = wr[0], w1 = wr[1];
      acc[0] += xi * w0.x; acc[1] += xi * w0.y; acc[2] += xi * w0.z; acc[3] += xi * w0.w;
      acc[4] += xi * w1.x; acc[5] += xi * w1.y; acc[6] += xi * w1.z; acc[7] += xi * w1.w;
    }
  }
#pragma unroll
  for (int off = 32; off > 0; off >>= 1)
#pragma unroll
    for (int e = 0; e < NEXP; e++) acc[e] += __shfl_xor(acc[e], off, 64);
  if (lane == 0) {
    float mx = acc[0]; int ai = 0;
#pragma unroll
    for (int e = 1; e < NEXP; e++) if (acc[e] > mx) { mx = acc[e]; ai = e; }
    float ex[NEXP]; float se = 0.f;
#pragma unroll
    for (int e = 0; e < NEXP; e++) { ex[e] = __expf(acc[e] - mx); se += ex[e]; }
    float inv = 1.f / se;
#pragma unroll
    for (int e = 0; e < NEXP; e++) atomicAdd(&me_s[e], ex[e] * inv);
    idx[t] = ai;
    gate[t] = inv;
  }
  __syncthreads();
  if (tid < NEXP) mepart[blockIdx.x * NEXP + tid] = me_s[tid];
}

// ---------------- ordered scan: queue positions + l_aux tail ----------------
__global__ __launch_bounds__(1024) void scan_kernel(
    const int* __restrict__ idx, float* __restrict__ gate,
    int* __restrict__ s2t, int* __restrict__ counts,
    const float* __restrict__ mepart, float* __restrict__ out_tail) {
  __shared__ int wcnt[16][NEXP];
  __shared__ int wbase[16][NEXP];
  __shared__ int totc[NEXP];
  __shared__ float red2[1024];
  int tid = threadIdx.x, wid = tid >> 6, lane = tid & 63;
  unsigned long long ltmask = (1ull << lane) - 1ull;
  int myexp[16], myloc[16];
  int cnt[NEXP];
#pragma unroll
  for (int e = 0; e < NEXP; e++) cnt[e] = 0;
  int base_tok = wid * 1024;
#pragma unroll
  for (int p = 0; p < 16; p++) {
    int e = idx[base_tok + p * 64 + lane];
    myexp[p] = e;
    int pos = 0;
#pragma unroll
    for (int e2 = 0; e2 < NEXP; e2++) {
      unsigned long long b = __ballot(e == e2);
      if (e == e2) pos = cnt[e2] + __popcll(b & ltmask);
      cnt[e2] += __popcll(b);            // wave-uniform
    }
    myloc[p] = pos;
  }
  if (lane < NEXP) wcnt[wid][lane] = cnt[lane];
  __syncthreads();
  if (tid < 128) {
    int w = tid >> 3, e = tid & 7;
    int s = 0;
    for (int w2 = 0; w2 < w; w2++) s += wcnt[w2][e];
    wbase[w][e] = s;
  }
  __syncthreads();
#pragma unroll
  for (int p = 0; p < 16; p++) {
    int i = base_tok + p * 64 + lane;
    int e = myexp[p];
    int loc = wbase[wid][e] + myloc[p];
    if (loc < CAP) s2t[e * CAP + loc] = i;
    else           gate[i] = 0.f;
  }
  if (tid < NEXP) {
    int tot = 0;
#pragma unroll
    for (int w = 0; w < 16; w++) tot += wcnt[w][tid];
    counts[tid] = tot;
    totc[tid] = tot;
  }
  // ---- l_aux + exp_counts tail ----
  float s = 0.f;
  int e2 = tid & 7;
  for (int r = tid >> 3; r < (TOKENS / 4); r += 128) s += mepart[(size_t)r * NEXP + e2];
  red2[tid] = s;
  __syncthreads();
#pragma unroll
  for (int off = 512; off >= 8; off >>= 1) {
    if (tid < off) red2[tid] += red2[tid + off];
    __syncthreads();
  }
  if (tid == 0) {
    float la = 0.f;
    for (int k = 0; k < NEXP; k++)
      la += (red2[k] / (float)TOKENS) * ((float)totc[k] / (float)TOKENS);
    out_tail[0] = la * (float)NEXP;
  }
  if (tid < NEXP) out_tail[1 + tid] = (float)totc[tid];
}

// ---------------- fp32 [E][R][C] -> bf16 [E][C][R], 64x64 LDS tiles ----------------
__global__ __launch_bounds__(256) void transpose_cvt_kernel(
    const float* __restrict__ in, short* __restrict__ out, int R, int Cc) {
  __shared__ short tile[64][72];   // pad 72: 8B-aligned b64 reads, <=2-way banks
  int e = blockIdx.z;
  const float* in_e = in + (size_t)e * R * Cc;
  short* out_e = out + (size_t)e * R * Cc;
  int r0 = blockIdx.y * 64, c0 = blockIdx.x * 64;
  int tid = threadIdx.x;
#pragma unroll
  for (int i = 0; i < 4; i++) {
    int linear = tid + 256 * i;          // 0..1023
    int r = linear >> 4;                 // 0..63
    int f4 = linear & 15;                // 0..15
    float4 v = *(const float4*)(in_e + (size_t)(r0 + r) * Cc + c0 + f4 * 4);
    int c = f4 * 4;
    tile[c + 0][r] = f2bf(v.x);
    tile[c + 1][r] = f2bf(v.y);
    tile[c + 2][r] = f2bf(v.z);
    tile[c + 3][r] = f2bf(v.w);
  }
  __syncthreads();
#pragma unroll
  for (int i = 0; i < 4; i++) {
    int linear = tid + 256 * i;
    int c = linear >> 4;
    int s4 = linear & 15;
    short4 s;
    s.x = tile[c][s4 * 4 + 0]; s.y = tile[c][s4 * 4 + 1];
    s.z = tile[c][s4 * 4 + 2]; s.w = tile[c][s4 * 4 + 3];
    *(short4*)(out_e + (size_t)(c0 + c) * R + r0 + s4 * 4) = s;
  }
}

// ---------------- phase boundaries: counted vmcnt + raw barrier ----------------
__device__ __forceinline__ void vm_bar8() {
  asm volatile("s_waitcnt vmcnt(8)" ::: "memory");
  __builtin_amdgcn_s_barrier();
  asm volatile("" ::: "memory");
}
__device__ __forceinline__ void vm_bar0() {
  asm volatile("s_waitcnt vmcnt(0)" ::: "memory");
  __builtin_amdgcn_s_barrier();
  asm volatile("" ::: "memory");
}

#define GLL(gp, lp) __builtin_amdgcn_global_load_lds(                                   \
    (const __attribute__((address_space(1))) void*)(gp),                                \
    (__attribute__((address_space(3))) void*)(lp), 16, 0, 0)

// ---------------- GEMM1: 256x256xBK64, 8 waves, R0's 4-phase schedule (best measured) ----------------
// A = gathered xb rows (cap dim), B = W1t [H][M]. MFMA operands swapped:
// D[col=lane&15 -> cap row][row=(lane>>4)*4+j -> H col].
// LDS swizzle: LDS(r, s) = G(r, s ^ (r&7)) at 8-short granularity.
// Phases (16 MFMA each, single vm_bar8 at end):
//   P1: reads bf0(4)+af0(8)               ; MFMA rt0-3 x c0-1
//   P2: GLL A0+B0(t+2); reads bf1(4)      ; MFMA rt0-3 x c2-3
//   P3: GLL B1(t+2);    reads af1(8)      ; MFMA rt4-7 x c0-1
//   P4: GLL A1(t+2)                       ; MFMA rt4-7 x c2-3
// FIFO ledger: end-P2 drains A0B0(t+1); end-P3 drains B1(t+1); end-P4 drains A1(t+1)
// (each exactly just-in-time for its reader next tile). kk-outer MFMA for ILP.
__global__ __launch_bounds__(512, 2) void gemm1_kernel(
    const short* __restrict__ xb, const int* __restrict__ s2t,
    const short* __restrict__ W1t, const float* __restrict__ b1,
    short* __restrict__ Hh, const short* __restrict__ zrow, int eg) {
  __shared__ __align__(16) short ldsA[2][256 * 64];
  __shared__ __align__(16) short ldsB[2][256 * 64];
  int flat = blockIdx.x + 16 * blockIdx.y + 128 * blockIdx.z;   // nwg = 512
  int swz = (flat & 7) * 64 + (flat >> 3);                      // bijective (512 % 8 == 0)
  int bn = swz & 15, bm = (swz >> 4) & 7, bz = swz >> 7;
  int e_abs = eg + bz;
  int tid = threadIdx.x, lane = tid & 63, w = tid >> 6;
  int v = tid >> 3;                  // 0..63: row-within-round selector
  int sl = tid & 7;                  // source 16B slot selector

  // A staging pointers (token gather), rounds q=0..3: row = q*64 + v
  const short* aptr[4];
#pragma unroll
  for (int q = 0; q < 4; q++) {
    int r = q * 64 + v;
    int tok = s2t[e_abs * CAP + bm * 256 + r];
    const short* basep = (tok >= 0) ? (xb + (size_t)tok * MDIM) : zrow;
    aptr[q] = basep + ((sl ^ (r & 7)) * 8);
  }
  // B staging pointers, rounds (h,j): row = j*128 + (v>>5)*64 + (v&31) + h*32
  // (32-row interleave so bf0 rows are h0-staged, bf1 rows h1-staged)
  const short* Be = W1t + ((size_t)e_abs * HDIM + (size_t)bn * 256) * MDIM;
  const short* bptr[2][2];
#pragma unroll
  for (int h = 0; h < 2; h++)
#pragma unroll
    for (int j = 0; j < 2; j++) {
      int r = j * 128 + (v >> 5) * 64 + (v & 31) + h * 32;
      bptr[h][j] = Be + (size_t)r * MDIM + ((sl ^ (r & 7)) * 8);
    }
  asm volatile("" ::: "memory");   // pin gather loads before first stage

  // wave-uniform LDS destination bases (shorts)
  int ldsa_base[4], ldsb_base[2][2];
#pragma unroll
  for (int q = 0; q < 4; q++) ldsa_base[q] = (q * 64 + w * 8) * 64;
#pragma unroll
  for (int h = 0; h < 2; h++)
#pragma unroll
    for (int j = 0; j < 2; j++)
      ldsb_base[h][j] = (j * 128 + h * 32 + (w >> 2) * 64 + (w & 3) * 8) * 64;

  // prologue: tiles 0 and 1 fully staged (order A0,B0,B1,A1 per tile)
  GLL(aptr[0] + 0,        &ldsA[0][ldsa_base[0]]);
  GLL(aptr[2] + 0,        &ldsA[0][ldsa_base[2]]);
  GLL(bptr[0][0] + 0,     &ldsB[0][ldsb_base[0][0]]);
  GLL(bptr[0][1] + 0,     &ldsB[0][ldsb_base[0][1]]);
  GLL(bptr[1][0] + 0,     &ldsB[0][ldsb_base[1][0]]);
  GLL(bptr[1][1] + 0,     &ldsB[0][ldsb_base[1][1]]);
  GLL(aptr[1] + 0,        &ldsA[0][ldsa_base[1]]);
  GLL(aptr[3] + 0,        &ldsA[0][ldsa_base[3]]);
  GLL(aptr[0] + 64,       &ldsA[1][ldsa_base[0]]);
  GLL(aptr[2] + 64,       &ldsA[1][ldsa_base[2]]);
  GLL(bptr[0][0] + 64,    &ldsB[1][ldsb_base[0][0]]);
  GLL(bptr[0][1] + 64,    &ldsB[1][ldsb_base[0][1]]);
  GLL(bptr[1][0] + 64,    &ldsB[1][ldsb_base[1][0]]);
  GLL(bptr[1][1] + 64,    &ldsB[1][ldsb_base[1][1]]);
  GLL(aptr[1] + 64,       &ldsA[1][ldsa_base[1]]);
  GLL(aptr[3] + 64,       &ldsA[1][ldsa_base[3]]);
  vm_bar8();                          // tile 0 landed; tile 1 (8 loads) in flight

  int wm = w >> 2, wn = w & 3;       // 2 x 4 wave grid; per-wave out = 128(cap) x 64(H)
  int ln = lane & 15, q4 = lane >> 4;
  int offk0 = ((q4 ^ (lane & 7)) * 8);
  int offk1 = (((4 + q4) ^ (lane & 7)) * 8);
  int arowbase = wm * 128 + ln;
  int browbase = wn * 64 + ln;

  f32x4 acc[8][4];
  f32x4 zero = {0.f, 0.f, 0.f, 0.f};
#pragma unroll
  for (int a = 0; a < 8; a++)
#pragma unroll
    for (int b = 0; b < 4; b++) acc[a][b] = zero;

  for (int t = 0; t < NKT1; ++t) {
    int cur = t & 1;
    const short* La = ldsA[cur];
    const short* Lb = ldsB[cur];
    int kts = (t + 2) * 64;
    bool st = (t + 2) < NKT1;
    bool steady = t < (NKT1 - 2);
    bf16x8 af[4][2], bf0[2][2], bf1[2][2];
    // ---- P1: reads bf0 first, then af0; MFMA rt0-3 x c0-1 (kk-outer) ----
#pragma unroll
    for (int c = 0; c < 2; c++) {
      int ro = (browbase + c * 16) * 64;
      bf0[c][0] = *(const bf16x8*)(Lb + ro + offk0);
      bf0[c][1] = *(const bf16x8*)(Lb + ro + offk1);
    }
#pragma unroll
    for (int rt = 0; rt < 4; rt++) {
      int ro = (arowbase + rt * 16) * 64;
      af[rt][0] = *(const bf16x8*)(La + ro + offk0);
      af[rt][1] = *(const bf16x8*)(La + ro + offk1);
    }
    __builtin_amdgcn_s_setprio(1);
#pragma unroll
    for (int kk = 0; kk < 2; kk++)
#pragma unroll
      for (int rt = 0; rt < 4; rt++)
#pragma unroll
        for (int c = 0; c < 2; c++)
          acc[rt][c] = __builtin_amdgcn_mfma_f32_16x16x32_bf16(bf0[c][kk], af[rt][kk], acc[rt][c], 0, 0, 0);
    __builtin_amdgcn_s_setprio(0);
    if (steady) vm_bar8(); else vm_bar0();
    // ---- P2: GLL A0+B0(t+2); reads bf1; MFMA rt0-3 x c2-3 ----
    if (st) {
      GLL(aptr[0] + kts,    &ldsA[cur][ldsa_base[0]]);
      GLL(aptr[2] + kts,    &ldsA[cur][ldsa_base[2]]);
      GLL(bptr[0][0] + kts, &ldsB[cur][ldsb_base[0][0]]);
      GLL(bptr[0][1] + kts, &ldsB[cur][ldsb_base[0][1]]);
    }
#pragma unroll
    for (int c = 0; c < 2; c++) {
      int ro = (browbase + (c + 2) * 16) * 64;
      bf1[c][0] = *(const bf16x8*)(Lb + ro + offk0);
      bf1[c][1] = *(const bf16x8*)(Lb + ro + offk1);
    }
    __builtin_amdgcn_s_setprio(1);
#pragma unroll
    for (int kk = 0; kk < 2; kk++)
#pragma unroll
      for (int rt = 0; rt < 4; rt++)
#pragma unroll
        for (int c = 0; c < 2; c++)
          acc[rt][c + 2] = __builtin_amdgcn_mfma_f32_16x16x32_bf16(bf1[c][kk], af[rt][kk], acc[rt][c + 2], 0, 0, 0);
    __builtin_amdgcn_s_setprio(0);
    if (steady) vm_bar8(); else vm_bar0();
    // ---- P3: GLL B1(t+2); reads af1 (overwrite af); MFMA rt4-7 x c0-1 ----
    if (st) {
      GLL(bptr[1][0] + kts, &ldsB[cur][ldsb_base[1][0]]);
      GLL(bptr[1][1] + kts, &ldsB[cur][ldsb_base[1][1]]);
    }
#pragma unroll
    for (int rt = 0; rt < 4; rt++) {
      int ro = (arowbase + 64 + rt * 16) * 64;
      af[rt][0] = *(const bf16x8*)(La + ro + offk0);
      af[rt][1] = *(const bf16x8*)(La + ro + offk1);
    }
    __builtin_amdgcn_s_setprio(1);
#pragma unroll
    for (int kk = 0; kk < 2; kk++)
#pragma unroll
      for (int rt = 0; rt < 4; rt++)
#pragma unroll
        for (int c = 0; c < 2; c++)
          acc[4 + rt][c] = __builtin_amdgcn_mfma_f32_16x16x32_bf16(bf0[c][kk], af[rt][kk], acc[4 + rt][c], 0, 0, 0);
    __builtin_amdgcn_s_setprio(0);
    if (steady) vm_bar8(); else vm_bar0();
    // ---- P4: GLL A1(t+2); MFMA rt4-7 x c2-3 ----
    if (st) {
      GLL(aptr[1] + kts,    &ldsA[cur][ldsa_base[1]]);
      GLL(aptr[3] + kts,    &ldsA[cur][ldsa_base[3]]);
    }
    __builtin_amdgcn_s_setprio(1);
#pragma unroll
    for (int kk = 0; kk < 2; kk++)
#pragma unroll
      for (int rt = 0; rt < 4; rt++)
#pragma unroll
        for (int c = 0; c < 2; c++)
          acc[4 + rt][c + 2] = __builtin_amdgcn_mfma_f32_16x16x32_bf16(bf1[c][kk], af[rt][kk], acc[4 + rt][c + 2], 0, 0, 0);
    __builtin_amdgcn_s_setprio(0);
    if (steady) vm_bar8(); else vm_bar0();
  }

  // epilogue: gelu + bias -> bf16 pack -> 8B stores
#pragma unroll
  for (int rt = 0; rt < 8; rt++) {
    int caprow = bm * 256 + wm * 128 + rt * 16 + ln;
    size_t rowoff = ((size_t)bz * CAP + caprow) * HDIM;
#pragma unroll
    for (int c = 0; c < 4; c++) {
      int colb = bn * 256 + wn * 64 + c * 16 + q4 * 4;
      float4 bias = *(const float4*)(b1 + (size_t)e_abs * HDIM + colb);
      unsigned u0 = bfbits(gelu_f(acc[rt][c][0] + bias.x));
      unsigned u1 = bfbits(gelu_f(acc[rt][c][1] + bias.y));
      unsigned u2 = bfbits(gelu_f(acc[rt][c][2] + bias.z));
      unsigned u3 = bfbits(gelu_f(acc[rt][c][3] + bias.w));
      uint2 pk;
      pk.x = __builtin_amdgcn_perm(u1, u0, 0x07060302u);
      pk.y = __builtin_amdgcn_perm(u3, u2, 0x07060302u);
      *(uint2*)(Hh + rowoff + colb) = pk;
    }
  }
}

// ---------------- GEMM2: 128x128xBK64, 4 waves, 64 KiB LDS -> 2 blocks/CU (m97-style) ----------------
// A = Hh [cap][H] (dense), B = W2t [M][H]. Per-wave out = 64(cap) x 64(M), wave grid 2x2.
// Per tile: issue stage(t+1)->buf[t+1&1] (8 GLL); read bf(8)+af(8); 32 MFMA kk-outer; vm_bar0.
// The vmcnt(0) drain is hidden by the co-resident second block (cross-block overlap).
__global__ __launch_bounds__(256, 2) void gemm2_kernel(
    const short* __restrict__ Hh, const short* __restrict__ W2t,
    const float* __restrict__ b2, const int* __restrict__ s2t,
    const float* __restrict__ gate, float* __restrict__ out, int eg) {
  __shared__ __align__(16) short ldsA[2][128 * 64];
  __shared__ __align__(16) short ldsB[2][128 * 64];
  int flat = blockIdx.x + 8 * blockIdx.y + 128 * blockIdx.z;    // nwg = 512
  int swz = (flat & 7) * 64 + (flat >> 3);                      // bijective (512 % 8 == 0)
  int bn = swz & 7, bm = (swz >> 3) & 15, bz = swz >> 7;
  int e_abs = eg + bz;
  int tid = threadIdx.x, lane = tid & 63, w = tid >> 6;
  int v = tid >> 3, sl = tid & 7;    // v: 0..31 row selector, sl: 16B slot
  const short* Ae = Hh + ((size_t)bz * CAP + (size_t)bm * 128) * HDIM;
  const short* Be = W2t + ((size_t)e_abs * MDIM + (size_t)bn * 128) * HDIM;
  const short* aptr[4];
  const short* bptr[4];
#pragma unroll
  for (int q = 0; q < 4; q++) {
    int r = q * 32 + v;
    aptr[q] = Ae + (size_t)r * HDIM + ((sl ^ (r & 7)) * 8);
    bptr[q] = Be + (size_t)r * HDIM + ((sl ^ (r & 7)) * 8);
  }
  int lds_base[4];
#pragma unroll
  for (int q = 0; q < 4; q++) lds_base[q] = (q * 32 + w * 8) * 64;

  // prologue: stage tile 0, full drain
#pragma unroll
  for (int q = 0; q < 4; q++) GLL(aptr[q] + 0, &ldsA[0][lds_base[q]]);
#pragma unroll
  for (int q = 0; q < 4; q++) GLL(bptr[q] + 0, &ldsB[0][lds_base[q]]);
  vm_bar0();

  int wm = w >> 1, wn = w & 1;
  int ln = lane & 15, q4 = lane >> 4;
  int offk0 = ((q4 ^ (lane & 7)) * 8);
  int offk1 = (((4 + q4) ^ (lane & 7)) * 8);
  int arowbase = wm * 64 + ln;
  int browbase = wn * 64 + ln;

  f32x4 acc[4][4];
  f32x4 zero = {0.f, 0.f, 0.f, 0.f};
#pragma unroll
  for (int a = 0; a < 4; a++)
#pragma unroll
    for (int b = 0; b < 4; b++) acc[a][b] = zero;

  for (int t = 0; t < NKT2; ++t) {
    int cur = t & 1;
    const short* La = ldsA[cur];
    const short* Lb = ldsB[cur];
    // issue next tile's stage into the other buffer
    if (t + 1 < NKT2) {
      int k1 = (t + 1) * 64;
#pragma unroll
      for (int q = 0; q < 4; q++) GLL(aptr[q] + k1, &ldsA[cur ^ 1][lds_base[q]]);
#pragma unroll
      for (int q = 0; q < 4; q++) GLL(bptr[q] + k1, &ldsB[cur ^ 1][lds_base[q]]);
    }
    bf16x8 af[4][2], bf[4][2];
#pragma unroll
    for (int c = 0; c < 4; c++) {
      int ro = (browbase + c * 16) * 64;
      bf[c][0] = *(const bf16x8*)(Lb + ro + offk0);
      bf[c][1] = *(const bf16x8*)(Lb + ro + offk1);
    }
#pragma unroll
    for (int rt = 0; rt < 4; rt++) {
      int ro = (arowbase + rt * 16) * 64;
      af[rt][0] = *(const bf16x8*)(La + ro + offk0);
      af[rt][1] = *(const bf16x8*)(La + ro + offk1);
    }
    __builtin_amdgcn_s_setprio(1);
#pragma unroll
    for (int kk = 0; kk < 2; kk++)
#pragma unroll
      for (int rt = 0; rt < 4; rt++)
#pragma unroll
        for (int c = 0; c < 4; c++)
          acc[rt][c] = __builtin_amdgcn_mfma_f32_16x16x32_bf16(bf[c][kk], af[rt][kk], acc[rt][c], 0, 0, 0);
    __builtin_amdgcn_s_setprio(0);
    vm_bar0();                        // drain stage(t+1); hidden by 2nd block on CU
  }

  // epilogue: bias + gate scale, scatter to token rows
#pragma unroll
  for (int rt = 0; rt < 4; rt++) {
    int caprow = bm * 128 + wm * 64 + rt * 16 + ln;
    int token = s2t[e_abs * CAP + caprow];
    if (token < 0) continue;
    float g = gate[token];
    float* orow = out + (size_t)token * MDIM;
#pragma unroll
    for (int c = 0; c < 4; c++) {
      int colb = bn * 128 + wn * 64 + c * 16 + q4 * 4;
      float4 bias = *(const float4*)(b2 + (size_t)e_abs * MDIM + colb);
      float4 vv;
      vv.x = (acc[rt][c][0] + bias.x) * g;
      vv.y = (acc[rt][c][1] + bias.y) * g;
      vv.z = (acc[rt][c][2] + bias.z) * g;
      vv.w = (acc[rt][c][3] + bias.w) * g;
      *(float4*)(orow + colb) = vv;
    }
  }
}

// ---------------- zero rows of dropped tokens ----------------
__global__ __launch_bounds__(256) void zerodrop_kernel(
    const float* __restrict__ gate, float* __restrict__ out) {
  int t = blockIdx.x;
  if (gate[t] != 0.f) return;
  float4 z = {0.f, 0.f, 0.f, 0.f};
  ((float4*)(out + (size_t)t * MDIM))[threadIdx.x] = z;
}

extern "C" void kernel_launch(void* const* d_in, const int* in_sizes, int n_in,
                              void* d_out, int out_size, void* d_ws, size_t ws_size,
                              hipStream_t stream) {
  const float* x  = (const float*)d_in[0];
  const float* wg = (const float*)d_in[1];
  const float* w1 = (const float*)d_in[2];
  const float* b1 = (const float*)d_in[3];
  const float* w2 = (const float*)d_in[4];
  const float* b2 = (const float*)d_in[5];
  float* out = (float*)d_out;

  char* ws = (char*)d_ws;
  size_t off = 0;
  auto alloc = [&](size_t n) { char* ptr = ws + off; off += (n + 255) & ~(size_t)255; return ptr; };
  short* W1t  = (short*)alloc((size_t)NEXP * MDIM * HDIM * 2);   // 67 MB [E][H][M]
  short* W2t  = (short*)alloc((size_t)NEXP * MDIM * HDIM * 2);   // 67 MB [E][M][H]
  short* Hh   = (short*)alloc((size_t)EGRP * CAP * HDIM * 2);    // 67 MB (4 experts, full H)
  short* xb   = (short*)alloc((size_t)TOKENS * MDIM * 2);        // 33.5 MB bf16 x
  short* zrow = (short*)alloc((size_t)MDIM * 2);
  int*   idx  = (int*)  alloc(TOKENS * 4);
  float* gate = (float*)alloc(TOKENS * 4);
  int*   s2t  = (int*)  alloc(NEXP * CAP * 4);
  float* mep  = (float*)alloc((TOKENS / 4) * NEXP * 4);
  int*   cnts = (int*)  alloc(NEXP * 4);
  if (ws_size < off) return;

  hipMemsetAsync(s2t, 0xFF, NEXP * CAP * 4, stream);  // -1 sentinels
  hipMemsetAsync(zrow, 0, MDIM * 2, stream);

  gating_kernel<<<TOKENS / 4, 256, 0, stream>>>(x, wg, idx, gate, mep, xb);
  scan_kernel<<<1, 1024, 0, stream>>>(idx, gate, s2t, cnts, mep, out + (size_t)TOKENS * MDIM);
  transpose_cvt_kernel<<<dim3(HDIM / 64, MDIM / 64, NEXP), 256, 0, stream>>>(w1, W1t, MDIM, HDIM);
  transpose_cvt_kernel<<<dim3(MDIM / 64, HDIM / 64, NEXP), 256, 0, stream>>>(w2, W2t, HDIM, MDIM);
  for (int g = 0; g < 2; g++) {
    gemm1_kernel<<<dim3(HDIM / 256, CAP / 256, EGRP), 512, 0, stream>>>(xb, s2t, W1t, b1, Hh, zrow, g * EGRP);
    gemm2_kernel<<<dim3(MDIM / 128, CAP / 128, EGRP), 256, 0, stream>>>(Hh, W2t, b2, s2t, gate, out, g * EGRP);
  }
  zerodrop_kernel<<<TOKENS, 256, 0, stream>>>(gate, out);
}

// Round 5
// 833.481 us; speedup vs baseline: 1.1198x; 1.0144x over previous
//
#include <hip/hip_runtime.h>
#include <hip/hip_bf16.h>

#define TOKENS 16384
#define MDIM   1024
#define HDIM   4096
#define NEXP   8
#define EGRP   4          // experts per GEMM group (2 groups)
#define CAP    2048
#define NKT1   (MDIM / 64)   // 16 K-tiles for GEMM1
#define NKT2   (HDIM / 64)   // 64 K-tiles for GEMM2

typedef __attribute__((ext_vector_type(8))) short bf16x8;  // 8 bf16 = 4 VGPR
typedef __attribute__((ext_vector_type(4))) float f32x4;

__device__ __forceinline__ short f2bf(float x) {
  unsigned u = __float_as_uint(x);
  unsigned r = (u + 0x7fffu + ((u >> 16) & 1u)) >> 16;
  return (short)r;
}

// round bits to bf16 boundary (RNE), result in high 16 bits
__device__ __forceinline__ unsigned bfbits(float x) {
  unsigned u = __float_as_uint(x);
  return u + 0x7fffu + ((u >> 16) & 1u);
}

__device__ __forceinline__ float gelu_f(float x) {
  // jax.nn.gelu approximate=True
  float u = 1.5957691216057308f * (x + 0.044715f * x * x * x);
  float e = __expf(u);
  return x * (1.f - 1.f / (e + 1.f));
}

// ---------------- gating: logits -> softmax -> argmax; also emit bf16 x ----------------
__global__ __launch_bounds__(256) void gating_kernel(
    const float* __restrict__ x, const float* __restrict__ wg,
    int* __restrict__ idx, float* __restrict__ gate,
    float* __restrict__ mepart, short* __restrict__ xb) {
  __shared__ float me_s[NEXP];
  int tid = threadIdx.x, wid = tid >> 6, lane = tid & 63;
  if (tid < NEXP) me_s[tid] = 0.f;
  __syncthreads();
  int t = blockIdx.x * 4 + wid;
  float acc[NEXP];
#pragma unroll
  for (int e = 0; e < NEXP; e++) acc[e] = 0.f;
  const float4* xr = (const float4*)(x + (size_t)t * MDIM);
  short* xbr = xb + (size_t)t * MDIM + lane * 16;
#pragma unroll
  for (int j = 0; j < 4; j++) {
    float4 xv = xr[lane * 4 + j];
    short4 bv; bv.x = f2bf(xv.x); bv.y = f2bf(xv.y); bv.z = f2bf(xv.z); bv.w = f2bf(xv.w);
    ((short4*)(xbr))[j] = bv;
    int base = lane * 16 + j * 4;
    const float* xp = &xv.x;
#pragma unroll
    for (int i = 0; i < 4; i++) {
      float xi = xp[i];
      const float4* wr = (const float4*)(wg + (size_t)(base + i) * NEXP);
      float4 w0 = wr[0], w1 = wr[1];
      acc[0] += xi * w0.x; acc[1] += xi * w0.y; acc[2] += xi * w0.z; acc[3] += xi * w0.w;
      acc[4] += xi * w1.x; acc[5] += xi * w1.y; acc[6] += xi * w1.z; acc[7] += xi * w1.w;
    }
  }
#pragma unroll
  for (int off = 32; off > 0; off >>= 1)
#pragma unroll
    for (int e = 0; e < NEXP; e++) acc[e] += __shfl_xor(acc[e], off, 64);
  if (lane == 0) {
    float mx = acc[0]; int ai = 0;
#pragma unroll
    for (int e = 1; e < NEXP; e++) if (acc[e] > mx) { mx = acc[e]; ai = e; }
    float ex[NEXP]; float se = 0.f;
#pragma unroll
    for (int e = 0; e < NEXP; e++) { ex[e] = __expf(acc[e] - mx); se += ex[e]; }
    float inv = 1.f / se;
#pragma unroll
    for (int e = 0; e < NEXP; e++) atomicAdd(&me_s[e], ex[e] * inv);
    idx[t] = ai;
    gate[t] = inv;
  }
  __syncthreads();
  if (tid < NEXP) mepart[blockIdx.x * NEXP + tid] = me_s[tid];
}

// ---------------- ordered scan: queue positions + l_aux tail ----------------
__global__ __launch_bounds__(1024) void scan_kernel(
    const int* __restrict__ idx, float* __restrict__ gate,
    int* __restrict__ s2t, int* __restrict__ counts,
    const float* __restrict__ mepart, float* __restrict__ out_tail) {
  __shared__ int wcnt[16][NEXP];
  __shared__ int wbase[16][NEXP];
  __shared__ int totc[NEXP];
  __shared__ float red2[1024];
  int tid = threadIdx.x, wid = tid >> 6, lane = tid & 63;
  unsigned long long ltmask = (1ull << lane) - 1ull;
  int myexp[16], myloc[16];
  int cnt[NEXP];
#pragma unroll
  for (int e = 0; e < NEXP; e++) cnt[e] = 0;
  int base_tok = wid * 1024;
#pragma unroll
  for (int p = 0; p < 16; p++) {
    int e = idx[base_tok + p * 64 + lane];
    myexp[p] = e;
    int pos = 0;
#pragma unroll
    for (int e2 = 0; e2 < NEXP; e2++) {
      unsigned long long b = __ballot(e == e2);
      if (e == e2) pos = cnt[e2] + __popcll(b & ltmask);
      cnt[e2] += __popcll(b);            // wave-uniform
    }
    myloc[p] = pos;
  }
  if (lane < NEXP) wcnt[wid][lane] = cnt[lane];
  __syncthreads();
  if (tid < 128) {
    int w = tid >> 3, e = tid & 7;
    int s = 0;
    for (int w2 = 0; w2 < w; w2++) s += wcnt[w2][e];
    wbase[w][e] = s;
  }
  __syncthreads();
#pragma unroll
  for (int p = 0; p < 16; p++) {
    int i = base_tok + p * 64 + lane;
    int e = myexp[p];
    int loc = wbase[wid][e] + myloc[p];
    if (loc < CAP) s2t[e * CAP + loc] = i;
    else           gate[i] = 0.f;
  }
  if (tid < NEXP) {
    int tot = 0;
#pragma unroll
    for (int w = 0; w < 16; w++) tot += wcnt[w][tid];
    counts[tid] = tot;
    totc[tid] = tot;
  }
  // ---- l_aux + exp_counts tail ----
  float s = 0.f;
  int e2 = tid & 7;
  for (int r = tid >> 3; r < (TOKENS / 4); r += 128) s += mepart[(size_t)r * NEXP + e2];
  red2[tid] = s;
  __syncthreads();
#pragma unroll
  for (int off = 512; off >= 8; off >>= 1) {
    if (tid < off) red2[tid] += red2[tid + off];
    __syncthreads();
  }
  if (tid == 0) {
    float la = 0.f;
    for (int k = 0; k < NEXP; k++)
      la += (red2[k] / (float)TOKENS) * ((float)totc[k] / (float)TOKENS);
    out_tail[0] = la * (float)NEXP;
  }
  if (tid < NEXP) out_tail[1 + tid] = (float)totc[tid];
}

// ---------------- fp32 [E][R][C] -> bf16 [E][C][R], 64x64 LDS tiles ----------------
__global__ __launch_bounds__(256) void transpose_cvt_kernel(
    const float* __restrict__ in, short* __restrict__ out, int R, int Cc) {
  __shared__ short tile[64][72];   // pad 72: 8B-aligned b64 reads, <=2-way banks
  int e = blockIdx.z;
  const float* in_e = in + (size_t)e * R * Cc;
  short* out_e = out + (size_t)e * R * Cc;
  int r0 = blockIdx.y * 64, c0 = blockIdx.x * 64;
  int tid = threadIdx.x;
#pragma unroll
  for (int i = 0; i < 4; i++) {
    int linear = tid + 256 * i;          // 0..1023
    int r = linear >> 4;                 // 0..63
    int f4 = linear & 15;                // 0..15
    float4 v = *(const float4*)(in_e + (size_t)(r0 + r) * Cc + c0 + f4 * 4);
    int c = f4 * 4;
    tile[c + 0][r] = f2bf(v.x);
    tile[c + 1][r] = f2bf(v.y);
    tile[c + 2][r] = f2bf(v.z);
    tile[c + 3][r] = f2bf(v.w);
  }
  __syncthreads();
#pragma unroll
  for (int i = 0; i < 4; i++) {
    int linear = tid + 256 * i;
    int c = linear >> 4;
    int s4 = linear & 15;
    short4 s;
    s.x = tile[c][s4 * 4 + 0]; s.y = tile[c][s4 * 4 + 1];
    s.z = tile[c][s4 * 4 + 2]; s.w = tile[c][s4 * 4 + 3];
    *(short4*)(out_e + (size_t)(c0 + c) * R + r0 + s4 * 4) = s;
  }
}

// ---------------- phase boundaries: counted vmcnt + raw barrier ----------------
__device__ __forceinline__ void vm_bar8() {
  asm volatile("s_waitcnt vmcnt(8)" ::: "memory");
  __builtin_amdgcn_s_barrier();
  asm volatile("" ::: "memory");
}
__device__ __forceinline__ void vm_bar0() {
  asm volatile("s_waitcnt vmcnt(0)" ::: "memory");
  __builtin_amdgcn_s_barrier();
  asm volatile("" ::: "memory");
}

#define GLL(gp, lp) __builtin_amdgcn_global_load_lds(                                   \
    (const __attribute__((address_space(1))) void*)(gp),                                \
    (__attribute__((address_space(3))) void*)(lp), 16, 0, 0)

// ---------------- GEMM1 (arm A, g=0): R0's exact 4-phase schedule, no swizzle ----------------
// Measured 104 us @26.9% MfmaUtil in R0. Natural blockIdx order; af-first reads;
// dependent-pair MFMA; single vm_bar8 per phase end.
__global__ __launch_bounds__(512, 2) void gemm1_kernel(
    const short* __restrict__ xb, const int* __restrict__ s2t,
    const short* __restrict__ W1t, const float* __restrict__ b1,
    short* __restrict__ Hh, const short* __restrict__ zrow, int eg) {
  __shared__ __align__(16) short ldsA[2][256 * 64];
  __shared__ __align__(16) short ldsB[2][256 * 64];
  int bz = blockIdx.z, bm = blockIdx.y, bn = blockIdx.x;
  int e_abs = eg + bz;
  int tid = threadIdx.x, lane = tid & 63, w = tid >> 6;
  int v = tid >> 3;                  // 0..63: row-within-round selector
  int sl = tid & 7;                  // source 16B slot selector

  // A staging pointers (token gather), rounds q=0..3: row = q*64 + v
  const short* aptr[4];
#pragma unroll
  for (int q = 0; q < 4; q++) {
    int r = q * 64 + v;
    int tok = s2t[e_abs * CAP + bm * 256 + r];
    const short* basep = (tok >= 0) ? (xb + (size_t)tok * MDIM) : zrow;
    aptr[q] = basep + ((sl ^ (r & 7)) * 8);
  }
  // B staging pointers, rounds (h,j): row = j*128 + (v>>5)*64 + (v&31) + h*32
  const short* Be = W1t + ((size_t)e_abs * HDIM + (size_t)bn * 256) * MDIM;
  const short* bptr[2][2];
#pragma unroll
  for (int h = 0; h < 2; h++)
#pragma unroll
    for (int j = 0; j < 2; j++) {
      int r = j * 128 + (v >> 5) * 64 + (v & 31) + h * 32;
      bptr[h][j] = Be + (size_t)r * MDIM + ((sl ^ (r & 7)) * 8);
    }
  asm volatile("" ::: "memory");   // pin gather loads before first stage

  // wave-uniform LDS destination bases (shorts)
  int ldsa_base[4], ldsb_base[2][2];
#pragma unroll
  for (int q = 0; q < 4; q++) ldsa_base[q] = (q * 64 + w * 8) * 64;
#pragma unroll
  for (int h = 0; h < 2; h++)
#pragma unroll
    for (int j = 0; j < 2; j++)
      ldsb_base[h][j] = (j * 128 + h * 32 + (w >> 2) * 64 + (w & 3) * 8) * 64;

  // prologue: tiles 0 and 1 fully staged (order A0,B0,B1,A1 per tile)
  GLL(aptr[0] + 0,        &ldsA[0][ldsa_base[0]]);
  GLL(aptr[2] + 0,        &ldsA[0][ldsa_base[2]]);
  GLL(bptr[0][0] + 0,     &ldsB[0][ldsb_base[0][0]]);
  GLL(bptr[0][1] + 0,     &ldsB[0][ldsb_base[0][1]]);
  GLL(bptr[1][0] + 0,     &ldsB[0][ldsb_base[1][0]]);
  GLL(bptr[1][1] + 0,     &ldsB[0][ldsb_base[1][1]]);
  GLL(aptr[1] + 0,        &ldsA[0][ldsa_base[1]]);
  GLL(aptr[3] + 0,        &ldsA[0][ldsa_base[3]]);
  GLL(aptr[0] + 64,       &ldsA[1][ldsa_base[0]]);
  GLL(aptr[2] + 64,       &ldsA[1][ldsa_base[2]]);
  GLL(bptr[0][0] + 64,    &ldsB[1][ldsb_base[0][0]]);
  GLL(bptr[0][1] + 64,    &ldsB[1][ldsb_base[0][1]]);
  GLL(bptr[1][0] + 64,    &ldsB[1][ldsb_base[1][0]]);
  GLL(bptr[1][1] + 64,    &ldsB[1][ldsb_base[1][1]]);
  GLL(aptr[1] + 64,       &ldsA[1][ldsa_base[1]]);
  GLL(aptr[3] + 64,       &ldsA[1][ldsa_base[3]]);
  vm_bar8();                          // tile 0 landed; tile 1 (8 loads) in flight

  int wm = w >> 2, wn = w & 3;       // 2 x 4 wave grid; per-wave out = 128(cap) x 64(H)
  int ln = lane & 15, q4 = lane >> 4;
  int offk0 = ((q4 ^ (lane & 7)) * 8);
  int offk1 = (((4 + q4) ^ (lane & 7)) * 8);
  int arowbase = wm * 128 + ln;
  int browbase = wn * 64 + ln;

  f32x4 acc[8][4];
  f32x4 zero = {0.f, 0.f, 0.f, 0.f};
#pragma unroll
  for (int a = 0; a < 8; a++)
#pragma unroll
    for (int b = 0; b < 4; b++) acc[a][b] = zero;

  for (int t = 0; t < NKT1; ++t) {
    int cur = t & 1;
    const short* La = ldsA[cur];
    const short* Lb = ldsB[cur];
    int kts = (t + 2) * 64;
    bool st = (t + 2) < NKT1;
    bool steady = t < (NKT1 - 2);
    bf16x8 af[4][2], bf0[2][2], bf1[2][2];
    // ---- P1: read af0 + bf0; MFMA rt0-3 x c0-1 ----
#pragma unroll
    for (int rt = 0; rt < 4; rt++) {
      int ro = (arowbase + rt * 16) * 64;
      af[rt][0] = *(const bf16x8*)(La + ro + offk0);
      af[rt][1] = *(const bf16x8*)(La + ro + offk1);
    }
#pragma unroll
    for (int c = 0; c < 2; c++) {
      int ro = (browbase + c * 16) * 64;
      bf0[c][0] = *(const bf16x8*)(Lb + ro + offk0);
      bf0[c][1] = *(const bf16x8*)(Lb + ro + offk1);
    }
    __builtin_amdgcn_s_setprio(1);
#pragma unroll
    for (int rt = 0; rt < 4; rt++)
#pragma unroll
      for (int c = 0; c < 2; c++) {
        acc[rt][c] = __builtin_amdgcn_mfma_f32_16x16x32_bf16(bf0[c][0], af[rt][0], acc[rt][c], 0, 0, 0);
        acc[rt][c] = __builtin_amdgcn_mfma_f32_16x16x32_bf16(bf0[c][1], af[rt][1], acc[rt][c], 0, 0, 0);
      }
    __builtin_amdgcn_s_setprio(0);
    if (steady) vm_bar8(); else vm_bar0();
    // ---- P2: read bf1; GLL A0+B0(t+2); MFMA rt0-3 x c2-3 ----
#pragma unroll
    for (int c = 0; c < 2; c++) {
      int ro = (browbase + (c + 2) * 16) * 64;
      bf1[c][0] = *(const bf16x8*)(Lb + ro + offk0);
      bf1[c][1] = *(const bf16x8*)(Lb + ro + offk1);
    }
    if (st) {
      GLL(aptr[0] + kts,    &ldsA[cur][ldsa_base[0]]);
      GLL(aptr[2] + kts,    &ldsA[cur][ldsa_base[2]]);
      GLL(bptr[0][0] + kts, &ldsB[cur][ldsb_base[0][0]]);
      GLL(bptr[0][1] + kts, &ldsB[cur][ldsb_base[0][1]]);
    }
    __builtin_amdgcn_s_setprio(1);
#pragma unroll
    for (int rt = 0; rt < 4; rt++)
#pragma unroll
      for (int c = 0; c < 2; c++) {
        acc[rt][c + 2] = __builtin_amdgcn_mfma_f32_16x16x32_bf16(bf1[c][0], af[rt][0], acc[rt][c + 2], 0, 0, 0);
        acc[rt][c + 2] = __builtin_amdgcn_mfma_f32_16x16x32_bf16(bf1[c][1], af[rt][1], acc[rt][c + 2], 0, 0, 0);
      }
    __builtin_amdgcn_s_setprio(0);
    if (steady) vm_bar8(); else vm_bar0();
    // ---- P3: read af1; GLL B1(t+2); MFMA rt4-7 x c0-1 ----
#pragma unroll
    for (int rt = 0; rt < 4; rt++) {
      int ro = (arowbase + 64 + rt * 16) * 64;
      af[rt][0] = *(const bf16x8*)(La + ro + offk0);
      af[rt][1] = *(const bf16x8*)(La + ro + offk1);
    }
    if (st) {
      GLL(bptr[1][0] + kts, &ldsB[cur][ldsb_base[1][0]]);
      GLL(bptr[1][1] + kts, &ldsB[cur][ldsb_base[1][1]]);
    }
    __builtin_amdgcn_s_setprio(1);
#pragma unroll
    for (int rt = 0; rt < 4; rt++)
#pragma unroll
      for (int c = 0; c < 2; c++) {
        acc[4 + rt][c] = __builtin_amdgcn_mfma_f32_16x16x32_bf16(bf0[c][0], af[rt][0], acc[4 + rt][c], 0, 0, 0);
        acc[4 + rt][c] = __builtin_amdgcn_mfma_f32_16x16x32_bf16(bf0[c][1], af[rt][1], acc[4 + rt][c], 0, 0, 0);
      }
    __builtin_amdgcn_s_setprio(0);
    if (steady) vm_bar8(); else vm_bar0();
    // ---- P4: GLL A1(t+2); MFMA rt4-7 x c2-3 ----
    if (st) {
      GLL(aptr[1] + kts,    &ldsA[cur][ldsa_base[1]]);
      GLL(aptr[3] + kts,    &ldsA[cur][ldsa_base[3]]);
    }
    __builtin_amdgcn_s_setprio(1);
#pragma unroll
    for (int rt = 0; rt < 4; rt++)
#pragma unroll
      for (int c = 0; c < 2; c++) {
        acc[4 + rt][c + 2] = __builtin_amdgcn_mfma_f32_16x16x32_bf16(bf1[c][0], af[rt][0], acc[4 + rt][c + 2], 0, 0, 0);
        acc[4 + rt][c + 2] = __builtin_amdgcn_mfma_f32_16x16x32_bf16(bf1[c][1], af[rt][1], acc[4 + rt][c + 2], 0, 0, 0);
      }
    __builtin_amdgcn_s_setprio(0);
    if (steady) vm_bar8(); else vm_bar0();
  }

  // epilogue: gelu + bias -> bf16 pack -> 8B stores
#pragma unroll
  for (int rt = 0; rt < 8; rt++) {
    int caprow = bm * 256 + wm * 128 + rt * 16 + ln;
    size_t rowoff = ((size_t)bz * CAP + caprow) * HDIM;
#pragma unroll
    for (int c = 0; c < 4; c++) {
      int colb = bn * 256 + wn * 64 + c * 16 + q4 * 4;
      float4 bias = *(const float4*)(b1 + (size_t)e_abs * HDIM + colb);
      unsigned u0 = bfbits(gelu_f(acc[rt][c][0] + bias.x));
      unsigned u1 = bfbits(gelu_f(acc[rt][c][1] + bias.y));
      unsigned u2 = bfbits(gelu_f(acc[rt][c][2] + bias.z));
      unsigned u3 = bfbits(gelu_f(acc[rt][c][3] + bias.w));
      uint2 pk;
      pk.x = __builtin_amdgcn_perm(u1, u0, 0x07060302u);
      pk.y = __builtin_amdgcn_perm(u3, u2, 0x07060302u);
      *(uint2*)(Hh + rowoff + colb) = pk;
    }
  }
}

// ---------------- GEMM1 (arm B, g=1): m97-style 128x128, 4 waves, 2 blocks/CU ----------------
// Same structure as gemm2 (the R3 winner): stage(t+1) -> other buf, vm_bar0/tile,
// cross-block overlap hides the drain. Gathered A + gelu epilogue.
__global__ __launch_bounds__(256, 2) void gemm1_m97_kernel(
    const short* __restrict__ xb, const int* __restrict__ s2t,
    const short* __restrict__ W1t, const float* __restrict__ b1,
    short* __restrict__ Hh, const short* __restrict__ zrow, int eg) {
  __shared__ __align__(16) short ldsA[2][128 * 64];
  __shared__ __align__(16) short ldsB[2][128 * 64];
  int bz = blockIdx.z, bm = blockIdx.y, bn = blockIdx.x;   // bn: 0..31 (H), bm: 0..15 (cap)
  int e_abs = eg + bz;
  int tid = threadIdx.x, lane = tid & 63, w = tid >> 6;
  int v = tid >> 3, sl = tid & 7;    // v: 0..31 row selector, sl: 16B slot
  const short* Be = W1t + ((size_t)e_abs * HDIM + (size_t)bn * 128) * MDIM;
  const short* aptr[4];
  const short* bptr[4];
#pragma unroll
  for (int q = 0; q < 4; q++) {
    int r = q * 32 + v;
    int tok = s2t[e_abs * CAP + bm * 128 + r];
    const short* basep = (tok >= 0) ? (xb + (size_t)tok * MDIM) : zrow;
    aptr[q] = basep + ((sl ^ (r & 7)) * 8);
    bptr[q] = Be + (size_t)r * MDIM + ((sl ^ (r & 7)) * 8);
  }
  asm volatile("" ::: "memory");
  int lds_base[4];
#pragma unroll
  for (int q = 0; q < 4; q++) lds_base[q] = (q * 32 + w * 8) * 64;

  // prologue: stage tile 0, full drain
#pragma unroll
  for (int q = 0; q < 4; q++) GLL(aptr[q] + 0, &ldsA[0][lds_base[q]]);
#pragma unroll
  for (int q = 0; q < 4; q++) GLL(bptr[q] + 0, &ldsB[0][lds_base[q]]);
  vm_bar0();

  int wm = w >> 1, wn = w & 1;
  int ln = lane & 15, q4 = lane >> 4;
  int offk0 = ((q4 ^ (lane & 7)) * 8);
  int offk1 = (((4 + q4) ^ (lane & 7)) * 8);
  int arowbase = wm * 64 + ln;
  int browbase = wn * 64 + ln;

  f32x4 acc[4][4];
  f32x4 zero = {0.f, 0.f, 0.f, 0.f};
#pragma unroll
  for (int a = 0; a < 4; a++)
#pragma unroll
    for (int b = 0; b < 4; b++) acc[a][b] = zero;

  for (int t = 0; t < NKT1; ++t) {
    int cur = t & 1;
    const short* La = ldsA[cur];
    const short* Lb = ldsB[cur];
    if (t + 1 < NKT1) {
      int k1 = (t + 1) * 64;
#pragma unroll
      for (int q = 0; q < 4; q++) GLL(aptr[q] + k1, &ldsA[cur ^ 1][lds_base[q]]);
#pragma unroll
      for (int q = 0; q < 4; q++) GLL(bptr[q] + k1, &ldsB[cur ^ 1][lds_base[q]]);
    }
    bf16x8 af[4][2], bf[4][2];
#pragma unroll
    for (int c = 0; c < 4; c++) {
      int ro = (browbase + c * 16) * 64;
      bf[c][0] = *(const bf16x8*)(Lb + ro + offk0);
      bf[c][1] = *(const bf16x8*)(Lb + ro + offk1);
    }
#pragma unroll
    for (int rt = 0; rt < 4; rt++) {
      int ro = (arowbase + rt * 16) * 64;
      af[rt][0] = *(const bf16x8*)(La + ro + offk0);
      af[rt][1] = *(const bf16x8*)(La + ro + offk1);
    }
    __builtin_amdgcn_s_setprio(1);
#pragma unroll
    for (int kk = 0; kk < 2; kk++)
#pragma unroll
      for (int rt = 0; rt < 4; rt++)
#pragma unroll
        for (int c = 0; c < 4; c++)
          acc[rt][c] = __builtin_amdgcn_mfma_f32_16x16x32_bf16(bf[c][kk], af[rt][kk], acc[rt][c], 0, 0, 0);
    __builtin_amdgcn_s_setprio(0);
    vm_bar0();                        // drain stage(t+1); hidden by 2nd block on CU
  }

  // epilogue: gelu + bias -> bf16 pack -> 8B stores
#pragma unroll
  for (int rt = 0; rt < 4; rt++) {
    int caprow = bm * 128 + wm * 64 + rt * 16 + ln;
    size_t rowoff = ((size_t)bz * CAP + caprow) * HDIM;
#pragma unroll
    for (int c = 0; c < 4; c++) {
      int colb = bn * 128 + wn * 64 + c * 16 + q4 * 4;
      float4 bias = *(const float4*)(b1 + (size_t)e_abs * HDIM + colb);
      unsigned u0 = bfbits(gelu_f(acc[rt][c][0] + bias.x));
      unsigned u1 = bfbits(gelu_f(acc[rt][c][1] + bias.y));
      unsigned u2 = bfbits(gelu_f(acc[rt][c][2] + bias.z));
      unsigned u3 = bfbits(gelu_f(acc[rt][c][3] + bias.w));
      uint2 pk;
      pk.x = __builtin_amdgcn_perm(u1, u0, 0x07060302u);
      pk.y = __builtin_amdgcn_perm(u3, u2, 0x07060302u);
      *(uint2*)(Hh + rowoff + colb) = pk;
    }
  }
}

// ---------------- GEMM2: 128x128xBK64, 4 waves, 64 KiB LDS -> 2 blocks/CU (R3 winner) ----------------
__global__ __launch_bounds__(256, 2) void gemm2_kernel(
    const short* __restrict__ Hh, const short* __restrict__ W2t,
    const float* __restrict__ b2, const int* __restrict__ s2t,
    const float* __restrict__ gate, float* __restrict__ out, int eg) {
  __shared__ __align__(16) short ldsA[2][128 * 64];
  __shared__ __align__(16) short ldsB[2][128 * 64];
  int flat = blockIdx.x + 8 * blockIdx.y + 128 * blockIdx.z;    // nwg = 512
  int swz = (flat & 7) * 64 + (flat >> 3);                      // bijective (512 % 8 == 0)
  int bn = swz & 7, bm = (swz >> 3) & 15, bz = swz >> 7;
  int e_abs = eg + bz;
  int tid = threadIdx.x, lane = tid & 63, w = tid >> 6;
  int v = tid >> 3, sl = tid & 7;    // v: 0..31 row selector, sl: 16B slot
  const short* Ae = Hh + ((size_t)bz * CAP + (size_t)bm * 128) * HDIM;
  const short* Be = W2t + ((size_t)e_abs * MDIM + (size_t)bn * 128) * HDIM;
  const short* aptr[4];
  const short* bptr[4];
#pragma unroll
  for (int q = 0; q < 4; q++) {
    int r = q * 32 + v;
    aptr[q] = Ae + (size_t)r * HDIM + ((sl ^ (r & 7)) * 8);
    bptr[q] = Be + (size_t)r * HDIM + ((sl ^ (r & 7)) * 8);
  }
  int lds_base[4];
#pragma unroll
  for (int q = 0; q < 4; q++) lds_base[q] = (q * 32 + w * 8) * 64;

  // prologue: stage tile 0, full drain
#pragma unroll
  for (int q = 0; q < 4; q++) GLL(aptr[q] + 0, &ldsA[0][lds_base[q]]);
#pragma unroll
  for (int q = 0; q < 4; q++) GLL(bptr[q] + 0, &ldsB[0][lds_base[q]]);
  vm_bar0();

  int wm = w >> 1, wn = w & 1;
  int ln = lane & 15, q4 = lane >> 4;
  int offk0 = ((q4 ^ (lane & 7)) * 8);
  int offk1 = (((4 + q4) ^ (lane & 7)) * 8);
  int arowbase = wm * 64 + ln;
  int browbase = wn * 64 + ln;

  f32x4 acc[4][4];
  f32x4 zero = {0.f, 0.f, 0.f, 0.f};
#pragma unroll
  for (int a = 0; a < 4; a++)
#pragma unroll
    for (int b = 0; b < 4; b++) acc[a][b] = zero;

  for (int t = 0; t < NKT2; ++t) {
    int cur = t & 1;
    const short* La = ldsA[cur];
    const short* Lb = ldsB[cur];
    if (t + 1 < NKT2) {
      int k1 = (t + 1) * 64;
#pragma unroll
      for (int q = 0; q < 4; q++) GLL(aptr[q] + k1, &ldsA[cur ^ 1][lds_base[q]]);
#pragma unroll
      for (int q = 0; q < 4; q++) GLL(bptr[q] + k1, &ldsB[cur ^ 1][lds_base[q]]);
    }
    bf16x8 af[4][2], bf[4][2];
#pragma unroll
    for (int c = 0; c < 4; c++) {
      int ro = (browbase + c * 16) * 64;
      bf[c][0] = *(const bf16x8*)(Lb + ro + offk0);
      bf[c][1] = *(const bf16x8*)(Lb + ro + offk1);
    }
#pragma unroll
    for (int rt = 0; rt < 4; rt++) {
      int ro = (arowbase + rt * 16) * 64;
      af[rt][0] = *(const bf16x8*)(La + ro + offk0);
      af[rt][1] = *(const bf16x8*)(La + ro + offk1);
    }
    __builtin_amdgcn_s_setprio(1);
#pragma unroll
    for (int kk = 0; kk < 2; kk++)
#pragma unroll
      for (int rt = 0; rt < 4; rt++)
#pragma unroll
        for (int c = 0; c < 4; c++)
          acc[rt][c] = __builtin_amdgcn_mfma_f32_16x16x32_bf16(bf[c][kk], af[rt][kk], acc[rt][c], 0, 0, 0);
    __builtin_amdgcn_s_setprio(0);
    vm_bar0();                        // drain stage(t+1); hidden by 2nd block on CU
  }

  // epilogue: bias + gate scale, scatter to token rows
#pragma unroll
  for (int rt = 0; rt < 4; rt++) {
    int caprow = bm * 128 + wm * 64 + rt * 16 + ln;
    int token = s2t[e_abs * CAP + caprow];
    if (token < 0) continue;
    float g = gate[token];
    float* orow = out + (size_t)token * MDIM;
#pragma unroll
    for (int c = 0; c < 4; c++) {
      int colb = bn * 128 + wn * 64 + c * 16 + q4 * 4;
      float4 bias = *(const float4*)(b2 + (size_t)e_abs * MDIM + colb);
      float4 vv;
      vv.x = (acc[rt][c][0] + bias.x) * g;
      vv.y = (acc[rt][c][1] + bias.y) * g;
      vv.z = (acc[rt][c][2] + bias.z) * g;
      vv.w = (acc[rt][c][3] + bias.w) * g;
      *(float4*)(orow + colb) = vv;
    }
  }
}

// ---------------- zero rows of dropped tokens ----------------
__global__ __launch_bounds__(256) void zerodrop_kernel(
    const float* __restrict__ gate, float* __restrict__ out) {
  int t = blockIdx.x;
  if (gate[t] != 0.f) return;
  float4 z = {0.f, 0.f, 0.f, 0.f};
  ((float4*)(out + (size_t)t * MDIM))[threadIdx.x] = z;
}

extern "C" void kernel_launch(void* const* d_in, const int* in_sizes, int n_in,
                              void* d_out, int out_size, void* d_ws, size_t ws_size,
                              hipStream_t stream) {
  const float* x  = (const float*)d_in[0];
  const float* wg = (const float*)d_in[1];
  const float* w1 = (const float*)d_in[2];
  const float* b1 = (const float*)d_in[3];
  const float* w2 = (const float*)d_in[4];
  const float* b2 = (const float*)d_in[5];
  float* out = (float*)d_out;

  char* ws = (char*)d_ws;
  size_t off = 0;
  auto alloc = [&](size_t n) { char* ptr = ws + off; off += (n + 255) & ~(size_t)255; return ptr; };
  short* W1t  = (short*)alloc((size_t)NEXP * MDIM * HDIM * 2);   // 67 MB [E][H][M]
  short* W2t  = (short*)alloc((size_t)NEXP * MDIM * HDIM * 2);   // 67 MB [E][M][H]
  short* Hh   = (short*)alloc((size_t)EGRP * CAP * HDIM * 2);    // 67 MB (4 experts, full H)
  short* xb   = (short*)alloc((size_t)TOKENS * MDIM * 2);        // 33.5 MB bf16 x
  short* zrow = (short*)alloc((size_t)MDIM * 2);
  int*   idx  = (int*)  alloc(TOKENS * 4);
  float* gate = (float*)alloc(TOKENS * 4);
  int*   s2t  = (int*)  alloc(NEXP * CAP * 4);
  float* mep  = (float*)alloc((TOKENS / 4) * NEXP * 4);
  int*   cnts = (int*)  alloc(NEXP * 4);
  if (ws_size < off) return;

  hipMemsetAsync(s2t, 0xFF, NEXP * CAP * 4, stream);  // -1 sentinels
  hipMemsetAsync(zrow, 0, MDIM * 2, stream);

  gating_kernel<<<TOKENS / 4, 256, 0, stream>>>(x, wg, idx, gate, mep, xb);
  scan_kernel<<<1, 1024, 0, stream>>>(idx, gate, s2t, cnts, mep, out + (size_t)TOKENS * MDIM);
  transpose_cvt_kernel<<<dim3(HDIM / 64, MDIM / 64, NEXP), 256, 0, stream>>>(w1, W1t, MDIM, HDIM);
  transpose_cvt_kernel<<<dim3(MDIM / 64, HDIM / 64, NEXP), 256, 0, stream>>>(w2, W2t, HDIM, MDIM);
  // g=0: arm A (R0 4-phase, 256^2, 1 block/CU). g=1: arm B (m97 128^2, 2 blocks/CU).
  gemm1_kernel    <<<dim3(HDIM / 256, CAP / 256, EGRP), 512, 0, stream>>>(xb, s2t, W1t, b1, Hh, zrow, 0);
  gemm2_kernel    <<<dim3(MDIM / 128, CAP / 128, EGRP), 256, 0, stream>>>(Hh, W2t, b2, s2t, gate, out, 0);
  gemm1_m97_kernel<<<dim3(HDIM / 128, CAP / 128, EGRP), 256, 0, stream>>>(xb, s2t, W1t, b1, Hh, zrow, EGRP);
  gemm2_kernel    <<<dim3(MDIM / 128, CAP / 128, EGRP), 256, 0, stream>>>(Hh, W2t, b2, s2t, gate, out, EGRP);
  zerodrop_kernel<<<TOKENS, 256, 0, stream>>>(gate, out);
}